// Round 5
// baseline (500.193 us; speedup 1.0000x reference)
//
#include <hip/hip_runtime.h>
#include <math.h>
#include <type_traits>

typedef __bf16 bf16x8 __attribute__((ext_vector_type(8)));
typedef float f32x4 __attribute__((ext_vector_type(4)));
typedef unsigned int u32x4 __attribute__((ext_vector_type(4)));

#define B_TOT 16384
#define D_TOT 64
#define R_TOT 63
#define H_TOT 256
#define PK_TOT 24
#define PI_F 3.14159265358979323846f

// ws layout: W1F fragments then W2F fragments (u32 units)
#define W2F_BASE_U32 1032192u
#define WS_NEED 6193152u

#define MFMA16(a, b, c) __builtin_amdgcn_mfma_f32_16x16x32_bf16((a), (b), (c), 0, 0, 0)

__device__ __forceinline__ unsigned short bf16_rtne(float f) {
    unsigned u = __float_as_uint(f);
    unsigned rr = u + 0x7FFFu + ((u >> 16) & 1u);
    return (unsigned short)(rr >> 16);
}

// one v_cvt_pk_bf16_f32: packs rtne(a) | rtne(b)<<16 (no builtin on gfx950)
__device__ __forceinline__ unsigned cvt_pk_bf16(float a, float b) {
    unsigned r;
    asm("v_cvt_pk_bf16_f32 %0, %1, %2" : "=v"(r) : "v"(a), "v"(b));
    return r;
}

// split 4 f32 -> hi plane (truncated bf16 x4) + lo plane (rtne residual x4)
__device__ __forceinline__ void split4(const float* v, uint2& hi, uint2& lo) {
    unsigned u0 = __float_as_uint(v[0]), u1 = __float_as_uint(v[1]);
    unsigned u2 = __float_as_uint(v[2]), u3 = __float_as_uint(v[3]);
    hi.x = __builtin_amdgcn_perm(u1, u0, 0x07060302u);   // {u1.hi16, u0.hi16}
    hi.y = __builtin_amdgcn_perm(u3, u2, 0x07060302u);
    float r0 = v[0] - __uint_as_float(u0 & 0xFFFF0000u);
    float r1 = v[1] - __uint_as_float(u1 & 0xFFFF0000u);
    float r2 = v[2] - __uint_as_float(u2 & 0xFFFF0000u);
    float r3 = v[3] - __uint_as_float(u3 & 0xFFFF0000u);
    lo.x = cvt_pk_bf16(r0, r1);
    lo.y = cvt_pk_bf16(r2, r3);
}

__global__ void init_out_kernel(float* __restrict__ out) {
    int b = blockIdx.x * 256 + threadIdx.x;
    if (b < B_TOT) {
        out[(size_t)b * D_TOT] = 0.0f;            // x[:,0] = 0
        out[(size_t)B_TOT * D_TOT + b] = 0.0f;    // log_det = 0
    }
}

// ---------------- prep: weights -> split-bf16 MFMA fragments in ws ----------------
// Bias trick: b1[r] is stored in the free padded K-row (d=31 for r<=30, d=63 for r>=31);
// the main kernel forces the staged z at that row to 1.0, so GEMM1 emits z*W1m + b1.
__global__ void prep_weights(const float* __restrict__ W1,
                             const float* __restrict__ b1,
                             const float* __restrict__ W2,
                             unsigned int* __restrict__ wsf)
{
    int gid = blockIdx.x * 256 + threadIdx.x;
    if (gid >= 193536) return;
    float v[8];
    unsigned int* dst;
    if (gid < 129024) {
        int lane = gid & 63;
        int q = gid >> 6;
        int t = q & 1; q >>= 1;
        int nt = q & 15; int r = q >> 4;
        int n  = (nt << 4) + (lane & 15);
        int kb = (t << 5) + ((lane >> 4) << 3);
        int bias_d = (r <= 30) ? 31 : 63;
        #pragma unroll
        for (int j = 0; j < 8; ++j) {
            int d = kb + j;
            v[j] = (d <= r) ? W1[(size_t)(r * 64 + d) * 256 + n]
                 : (d == bias_d ? b1[(size_t)r * 256 + n] : 0.0f);
        }
        int frag = ((r * 16 + nt) * 2 + t) * 2;
        dst = wsf + ((size_t)frag * 64 + lane) * 4;
    } else {
        int g2 = gid - 129024;
        int lane = g2 & 63;
        int q = g2 >> 6;
        int ks = q & 7; q >>= 3;
        int nt = q & 1; int r = q >> 1;
        int n  = (nt << 4) + (lane & 15);
        int kb = (ks << 5) + ((lane >> 4) << 3);
        #pragma unroll
        for (int j = 0; j < 8; ++j) {
            int k = kb + j;
            v[j] = (n < PK_TOT) ? W2[(size_t)(r * 256 + k) * PK_TOT + n] : 0.0f;
        }
        int frag = ((r * 2 + nt) * 8 + ks) * 2;
        dst = wsf + W2F_BASE_U32 + ((size_t)frag * 64 + lane) * 4;
    }
    unsigned hw[4], lw[4];
    #pragma unroll
    for (int i = 0; i < 4; ++i) {
        float a = v[2 * i], b = v[2 * i + 1];
        unsigned ua = __float_as_uint(a), ub = __float_as_uint(b);
        float ra = a - __uint_as_float(ua & 0xFFFF0000u);
        float rb = b - __uint_as_float(ub & 0xFFFF0000u);
        hw[i] = (ua >> 16) | (ub & 0xFFFF0000u);
        lw[i] = (unsigned)bf16_rtne(ra) | ((unsigned)bf16_rtne(rb) << 16);
    }
    *reinterpret_cast<u32x4*>(dst)       = u32x4{hw[0], hw[1], hw[2], hw[3]};
    *reinterpret_cast<u32x4*>(dst + 256) = u32x4{lw[0], lw[1], lw[2], lw[3]};
}

// ---------------- main MFMA kernel: block = 64 batches x one r, 4 waves ----------------
// 32 KB LDS + 80 VGPR -> 5 blocks/CU (LDS-capped at exactly 160 KB).
// h is stored single-plane bf16 (RTNE); z/W1 and W2 keep hi/lo split.
__global__ __launch_bounds__(256, 5) void flow_mfma(
    const float* __restrict__ z, const unsigned int* __restrict__ wsf,
    const float* __restrict__ b2, float* __restrict__ out)
{
    const int r   = blockIdx.y;
    const int b0  = blockIdx.x << 6;
    const int tid = threadIdx.x;
    const int w   = tid >> 6;
    const int l   = tid & 63;
    const int l15 = l & 15, l4 = l >> 4, key = l & 7;

    __shared__ __align__(16) unsigned char sm[32768];

    // ---- stage z split (hi trunc / lo rtne); bias row forced to 1.0 ----
    {
        const int m  = tid >> 2;
        const int dq = (tid & 3) << 4;
        const float* zp = z + (size_t)(b0 + m) * 64 + dq;
        const int mkey = m & 7;
        const int bias_d = (r <= 30) ? 31 : 63;
        const int rel = bias_d - dq;            // in [0,16) only for the owning thread
        #pragma unroll
        for (int qq = 0; qq < 4; ++qq) {
            float4 val = *reinterpret_cast<const float4*>(zp + (qq << 2));
            int d0 = dq + (qq << 2);
            float vv[4] = {val.x, val.y, val.z, val.w};
            if ((rel >> 2) == qq) vv[rel & 3] = 1.0f;   // bias row -> 1.0 (exact split)
            uint2 hi, lo;
            split4(vv, hi, lo);
            int off = (m << 7) + ((((d0 >> 3)) ^ mkey) << 4) + (((d0 >> 2) & 1) << 3);
            *reinterpret_cast<uint2*>(sm + off) = hi;
            *reinterpret_cast<uint2*>(sm + 8192 + off) = lo;
        }
    }
    __syncthreads();

    // ---- GEMM1 (output-transposed): D1[n][m] = sum_d W1m[d][n] * z[m][d] (+ b1 via bias row) ----
    f32x4 acc1[4][4];     // [ntl][mt]
    #pragma unroll
    for (int a = 0; a < 4; ++a)
        #pragma unroll
        for (int b = 0; b < 4; ++b) acc1[a][b] = f32x4{0.f, 0.f, 0.f, 0.f};

    auto run_gemm1 = [&](auto FULLC) {
        constexpr bool FULL = decltype(FULLC)::value;
        constexpr int NT = FULL ? 2 : 1;
        bf16x8 zf[4][NT][2];   // [mt][t][plane]
        #pragma unroll
        for (int mt = 0; mt < 4; ++mt)
            #pragma unroll
            for (int t = 0; t < NT; ++t) {
                int m = (mt << 4) + l15;
                int off = (m << 7) + ((((t << 2) + l4) ^ key) << 4);
                zf[mt][t][0] = __builtin_bit_cast(bf16x8, *reinterpret_cast<u32x4*>(sm + off));
                zf[mt][t][1] = __builtin_bit_cast(bf16x8, *reinterpret_cast<u32x4*>(sm + 8192 + off));
            }
        const unsigned int* w1b = wsf + (size_t)((r * 16 + (w << 2)) * 4) * 256 + (l << 2);
        #pragma unroll
        for (int ntl = 0; ntl < 4; ++ntl) {
            bf16x8 af[NT][2];
            #pragma unroll
            for (int t = 0; t < NT; ++t)
                #pragma unroll
                for (int pl = 0; pl < 2; ++pl)
                    af[t][pl] = __builtin_bit_cast(bf16x8,
                        *reinterpret_cast<const u32x4*>(w1b + ((ntl * 4 + t * 2 + pl) << 8)));
            #pragma unroll
            for (int t = 0; t < NT; ++t) {
                #pragma unroll
                for (int mt = 0; mt < 4; ++mt)
                    acc1[ntl][mt] = MFMA16(af[t][0], zf[mt][t][0], acc1[ntl][mt]);
                #pragma unroll
                for (int mt = 0; mt < 4; ++mt)
                    acc1[ntl][mt] = MFMA16(af[t][0], zf[mt][t][1], acc1[ntl][mt]);
                #pragma unroll
                for (int mt = 0; mt < 4; ++mt)
                    acc1[ntl][mt] = MFMA16(af[t][1], zf[mt][t][0], acc1[ntl][mt]);
            }
        }
    };
    if (r >= 31) run_gemm1(std::true_type{});
    else         run_gemm1(std::false_type{});

    // relu + RTNE bf16 (single plane), write this wave's 64 h-columns into the half-tile
    auto write_h = [&]() {
        #pragma unroll
        for (int ntl = 0; ntl < 4; ++ntl) {
            #pragma unroll
            for (int mt = 0; mt < 4; ++mt) {
                float vv[4];
                #pragma unroll
                for (int i = 0; i < 4; ++i)
                    vv[i] = fmaxf(acc1[ntl][mt][i], 0.0f);
                uint2 hi;
                hi.x = cvt_pk_bf16(vv[0], vv[1]);
                hi.y = cvt_pk_bf16(vv[2], vv[3]);
                int m   = (mt << 4) + l15;
                int gl  = ((w & 1) << 3) + (ntl << 1) + (l4 >> 1);
                int off = (m << 8) + ((gl ^ key) << 4) + ((l4 & 1) << 3);
                *reinterpret_cast<uint2*>(sm + 16384 + off) = hi;
            }
        }
    };

    f32x4 acc2[2][4];     // [nt2][mt]  D2[n][m] = sum_k W2[k][n] h[m][k]
    #pragma unroll
    for (int a = 0; a < 2; ++a)
        #pragma unroll
        for (int b = 0; b < 4; ++b) acc2[a][b] = f32x4{0.f, 0.f, 0.f, 0.f};

    const unsigned int* w2b = wsf + W2F_BASE_U32 + (size_t)(r * 32) * 256 + (l << 2);
    auto gemm2 = [&](int p) {
        const int ks = (p << 2) + w;   // wave's global k-step (32 k each)
        bf16x8 wf[2][2];
        #pragma unroll
        for (int nt2 = 0; nt2 < 2; ++nt2)
            #pragma unroll
            for (int pl = 0; pl < 2; ++pl)
                wf[nt2][pl] = __builtin_bit_cast(bf16x8,
                    *reinterpret_cast<const u32x4*>(w2b + ((nt2 * 16 + ks * 2 + pl) << 8)));
        bf16x8 hfr[4];
        #pragma unroll
        for (int mt = 0; mt < 4; ++mt) {
            int m   = (mt << 4) + l15;
            int off = (m << 8) + ((((w << 2) + l4) ^ key) << 4);
            hfr[mt] = __builtin_bit_cast(bf16x8, *reinterpret_cast<u32x4*>(sm + 16384 + off));
        }
        #pragma unroll
        for (int nt2 = 0; nt2 < 2; ++nt2)
            #pragma unroll
            for (int mt = 0; mt < 4; ++mt)
                acc2[nt2][mt] = MFMA16(wf[nt2][0], hfr[mt], acc2[nt2][mt]);
        #pragma unroll
        for (int nt2 = 0; nt2 < 2; ++nt2)
            #pragma unroll
            for (int mt = 0; mt < 4; ++mt)
                acc2[nt2][mt] = MFMA16(wf[nt2][1], hfr[mt], acc2[nt2][mt]);
    };

    if (w < 2) write_h();       // waves 0,1 own h-cols 0..127
    __syncthreads();
    gemm2(0);                   // k = 0..127
    __syncthreads();
    if (w >= 2) write_h();      // h-cols 128..255 overwrite the half-tile
    __syncthreads();
    gemm2(1);                   // k = 128..255

    // ---- cross-wave reduce of raw via LDS (aliases dead z region) ----
    auto part_off = [&](int ph, int nt2, int mt) -> int {
        int m = (mt << 4) + l15;
        return (((ph << 6) + m) << 7) + ((((nt2 << 2) + l4) ^ key) << 4);
    };
    if (w < 2) {
        #pragma unroll
        for (int nt2 = 0; nt2 < 2; ++nt2)
            #pragma unroll
            for (int mt = 0; mt < 4; ++mt)
                *reinterpret_cast<f32x4*>(sm + part_off(w, nt2, mt)) = acc2[nt2][mt];
    }
    __syncthreads();
    if (w >= 2) {
        #pragma unroll
        for (int nt2 = 0; nt2 < 2; ++nt2)
            #pragma unroll
            for (int mt = 0; mt < 4; ++mt) {
                f32x4* p = reinterpret_cast<f32x4*>(sm + part_off(w - 2, nt2, mt));
                *p = *p + acc2[nt2][mt];
            }
    }
    __syncthreads();

    // ---- flow epilogue (fast transcendentals) ----
    #pragma unroll
    for (int mh = 0; mh < 2; ++mh) {
        const int m  = (mh << 5) + (tid >> 3);
        const int j  = tid & 7;
        const int mk = m & 7;
        float ra = b2[(size_t)r * 24 + j];
        float rb = b2[(size_t)r * 24 + 8 + j];
        float rr = b2[(size_t)r * 24 + 16 + j];
        #pragma unroll
        for (int ph = 0; ph < 2; ++ph) {
            const int base = (((ph << 6) + m) << 7);
            const int sub  = (j & 3) << 2;
            ra += *reinterpret_cast<float*>(sm + base + ((((j) >> 2) ^ mk) << 4) + sub);
            rb += *reinterpret_cast<float*>(sm + base + ((((8 + j) >> 2) ^ mk) << 4) + sub);
            rr += *reinterpret_cast<float*>(sm + base + ((((16 + j) >> 2) ^ mk) << 4) + sub);
        }
        float zi = z[(size_t)(b0 + m) * 64 + r + 1];
        // tan((zi - pi)/2) == -cos(zi/2)/sin(zi/2); clamp to avoid inf^2/inf^2 NaN at zi=0
        float s, c;
        __sincosf(zi * 0.5f, &s, &c);
        float t = -c * __builtin_amdgcn_rcpf(s);
        t = fminf(fmaxf(t, -1e8f), 1e8f);
        float al = __expf(ra);
        float g  = fmaf(al, t, rb);
        float X  = 2.0f * atanf(g) + PI_F;
        float dv = al * fmaf(t, t, 1.0f) * __builtin_amdgcn_rcpf(fmaf(g, g, 1.0f));
        float mx = rr;
        mx = fmaxf(mx, __shfl_xor(mx, 1));
        mx = fmaxf(mx, __shfl_xor(mx, 2));
        mx = fmaxf(mx, __shfl_xor(mx, 4));
        float e = __expf(rr - mx);
        float se = e, sx = e * X, sd = e * dv;
        se += __shfl_xor(se, 1); se += __shfl_xor(se, 2); se += __shfl_xor(se, 4);
        sx += __shfl_xor(sx, 1); sx += __shfl_xor(sx, 2); sx += __shfl_xor(sx, 4);
        sd += __shfl_xor(sd, 1); sd += __shfl_xor(sd, 2); sd += __shfl_xor(sd, 4);
        if (j == 0) {
            int gb = b0 + m;
            float rse = __builtin_amdgcn_rcpf(se);
            out[(size_t)gb * D_TOT + r + 1] = sx * rse;
            atomicAdd(&out[(size_t)B_TOT * D_TOT + gb], __logf(sd * rse));
        }
    }
}

// ---------------- fp32 fallback (round-1 kernel, known-correct) ----------------
__global__ __launch_bounds__(256, 2) void flow_fp32(
    const float* __restrict__ z,  const float* __restrict__ W1,
    const float* __restrict__ b1, const float* __restrict__ W2,
    const float* __restrict__ b2, float* __restrict__ out)
{
    const int r   = blockIdx.y;
    const int b0  = blockIdx.x * 32;
    const int tid = threadIdx.x;

    __shared__ float smem[16384];
    float* z_t  = smem;
    float* h_s  = smem + 2048;
    float* w2t  = smem + 2048 + 8192;
    float* part = w2t;

    #pragma unroll
    for (int it = 0; it < 2; ++it) {
        int idx4 = it * 256 + tid;
        int brow = idx4 >> 4;
        int dq   = (idx4 & 15) << 2;
        float4 v = *reinterpret_cast<const float4*>(&z[(size_t)(b0 + brow) * D_TOT + dq]);
        z_t[(dq + 0) * 32 + brow] = v.x;
        z_t[(dq + 1) * 32 + brow] = v.y;
        z_t[(dq + 2) * 32 + brow] = v.z;
        z_t[(dq + 3) * 32 + brow] = v.w;
    }
    #pragma unroll
    for (int it = 0; it < 6; ++it) {
        int idx4 = it * 256 + tid;
        int k  = idx4 / 6;
        int pq = (idx4 - k * 6) << 2;
        float4 v = *reinterpret_cast<const float4*>(&W2[(size_t)(r * H_TOT + k) * PK_TOT + pq]);
        int gk = k >> 2, kq = k & 3;
        w2t[(pq + 0) * 256 + (((gk) ^ ((pq + 0) & 7)) << 2) + kq] = v.x;
        w2t[(pq + 1) * 256 + (((gk) ^ ((pq + 1) & 7)) << 2) + kq] = v.y;
        w2t[(pq + 2) * 256 + (((gk) ^ ((pq + 2) & 7)) << 2) + kq] = v.z;
        w2t[(pq + 3) * 256 + (((gk) ^ ((pq + 3) & 7)) << 2) + kq] = v.w;
    }
    __syncthreads();

    const int rg = tid & 15;
    const int cg = tid >> 4;
    float acc[2][16];
    #pragma unroll
    for (int j = 0; j < 2; ++j)
        #pragma unroll
        for (int i = 0; i < 16; ++i) acc[j][i] = 0.0f;

    const float* w1p = W1 + (size_t)(r * D_TOT) * H_TOT + (cg << 4);
    #pragma unroll 4
    for (int d = 0; d <= r; ++d) {
        float2 zv = *reinterpret_cast<const float2*>(&z_t[d * 32 + (rg << 1)]);
        const float* wrow = w1p + (size_t)d * H_TOT;
        float wv[16];
        *reinterpret_cast<float4*>(&wv[0])  = *reinterpret_cast<const float4*>(wrow + 0);
        *reinterpret_cast<float4*>(&wv[4])  = *reinterpret_cast<const float4*>(wrow + 4);
        *reinterpret_cast<float4*>(&wv[8])  = *reinterpret_cast<const float4*>(wrow + 8);
        *reinterpret_cast<float4*>(&wv[12]) = *reinterpret_cast<const float4*>(wrow + 12);
        #pragma unroll
        for (int i = 0; i < 16; ++i) {
            acc[0][i] = fmaf(zv.x, wv[i], acc[0][i]);
            acc[1][i] = fmaf(zv.y, wv[i], acc[1][i]);
        }
    }
    {
        const int key = (rg >> 1) & 7;
        #pragma unroll
        for (int gi = 0; gi < 4; ++gi) {
            float4 bv = *reinterpret_cast<const float4*>(&b1[(size_t)r * H_TOT + (cg << 4) + (gi << 2)]);
            #pragma unroll
            for (int j = 0; j < 2; ++j) {
                float4 v;
                v.x = fmaxf(acc[j][4 * gi + 0] + bv.x, 0.0f);
                v.y = fmaxf(acc[j][4 * gi + 1] + bv.y, 0.0f);
                v.z = fmaxf(acc[j][4 * gi + 2] + bv.z, 0.0f);
                v.w = fmaxf(acc[j][4 * gi + 3] + bv.w, 0.0f);
                int bb = (rg << 1) + j;
                int g  = ((cg << 2) + gi) ^ key;
                *reinterpret_cast<float4*>(&h_s[bb * 256 + (g << 2)]) = v;
            }
        }
    }
    __syncthreads();

    const int wv_ = tid >> 6;
    const int ln  = tid & 63;
    const int bq  = ln & 7;
    const int pg  = ln >> 3;
    float acc2[4][3];
    #pragma unroll
    for (int j = 0; j < 4; ++j)
        #pragma unroll
        for (int i = 0; i < 3; ++i) acc2[j][i] = 0.0f;

    #pragma unroll
    for (int c = 0; c < 8; ++c) {
        int k0  = (wv_ << 6) + (c << 3);
        int gk0 = k0 >> 2;
        float w2r[3][8], hr[4][8];
        #pragma unroll
        for (int i = 0; i < 3; ++i) {
            int p = 3 * pg + i, pk = p & 7;
            *reinterpret_cast<float4*>(&w2r[i][0]) =
                *reinterpret_cast<const float4*>(&w2t[p * 256 + (((gk0 + 0) ^ pk) << 2)]);
            *reinterpret_cast<float4*>(&w2r[i][4]) =
                *reinterpret_cast<const float4*>(&w2t[p * 256 + (((gk0 + 1) ^ pk) << 2)]);
        }
        #pragma unroll
        for (int j = 0; j < 4; ++j) {
            int bb = 4 * bq + j;
            *reinterpret_cast<float4*>(&hr[j][0]) =
                *reinterpret_cast<const float4*>(&h_s[bb * 256 + (((gk0 + 0) ^ bq) << 2)]);
            *reinterpret_cast<float4*>(&hr[j][4]) =
                *reinterpret_cast<const float4*>(&h_s[bb * 256 + (((gk0 + 1) ^ bq) << 2)]);
        }
        #pragma unroll
        for (int kk = 0; kk < 8; ++kk)
            #pragma unroll
            for (int j = 0; j < 4; ++j)
                #pragma unroll
                for (int i = 0; i < 3; ++i)
                    acc2[j][i] = fmaf(hr[j][kk], w2r[i][kk], acc2[j][i]);
    }
    __syncthreads();
    #pragma unroll
    for (int j = 0; j < 4; ++j)
        #pragma unroll
        for (int i = 0; i < 3; ++i)
            part[((wv_ << 5) + 4 * bq + j) * PK_TOT + 3 * pg + i] = acc2[j][i];
    __syncthreads();

    {
        const int eb = tid >> 3;
        const int ej = tid & 7;
        float rawa = b2[(size_t)r * PK_TOT + ej];
        float rawb = b2[(size_t)r * PK_TOT + 8 + ej];
        float rawr = b2[(size_t)r * PK_TOT + 16 + ej];
        #pragma unroll
        for (int w = 0; w < 4; ++w) {
            rawa += part[((w << 5) + eb) * PK_TOT + ej];
            rawb += part[((w << 5) + eb) * PK_TOT + 8 + ej];
            rawr += part[((w << 5) + eb) * PK_TOT + 16 + ej];
        }
        float zi = z_t[(r + 1) * 32 + eb];
        float t  = tanf((zi - PI_F) * 0.5f);
        float al = expf(rawa);
        float g  = fmaf(al, t, rawb);
        float X  = 2.0f * atanf(g) + PI_F;
        float dv = al * (1.0f + t * t) / (1.0f + g * g);
        float m = rawr;
        m = fmaxf(m, __shfl_xor(m, 1));
        m = fmaxf(m, __shfl_xor(m, 2));
        m = fmaxf(m, __shfl_xor(m, 4));
        float e  = expf(rawr - m);
        float se = e, sx = e * X, sd = e * dv;
        se += __shfl_xor(se, 1); se += __shfl_xor(se, 2); se += __shfl_xor(se, 4);
        sx += __shfl_xor(sx, 1); sx += __shfl_xor(sx, 2); sx += __shfl_xor(sx, 4);
        sd += __shfl_xor(sd, 1); sd += __shfl_xor(sd, 2); sd += __shfl_xor(sd, 4);
        if (ej == 0) {
            int gb = b0 + eb;
            out[(size_t)gb * D_TOT + (r + 1)] = sx / se;
            atomicAdd(&out[(size_t)B_TOT * D_TOT + gb], logf(sd / se));
        }
    }
}

extern "C" void kernel_launch(void* const* d_in, const int* in_sizes, int n_in,
                              void* d_out, int out_size, void* d_ws, size_t ws_size,
                              hipStream_t stream) {
    const float* z  = (const float*)d_in[0];
    const float* W1 = (const float*)d_in[1];
    const float* b1 = (const float*)d_in[2];
    const float* W2 = (const float*)d_in[3];
    const float* b2 = (const float*)d_in[4];
    float* out = (float*)d_out;

    init_out_kernel<<<dim3(B_TOT / 256), dim3(256), 0, stream>>>(out);
    if (ws_size >= (size_t)WS_NEED) {
        prep_weights<<<dim3(756), dim3(256), 0, stream>>>(W1, b1, W2, (unsigned int*)d_ws);
        flow_mfma<<<dim3(B_TOT / 64, R_TOT), dim3(256), 0, stream>>>(
            z, (const unsigned int*)d_ws, b2, out);
    } else {
        flow_fp32<<<dim3(B_TOT / 32, R_TOT), dim3(256), 0, stream>>>(z, W1, b1, W2, b2, out);
    }
}

// Round 6
// 154.541 us; speedup vs baseline: 3.2366x; 3.2366x over previous
//
#include <hip/hip_runtime.h>
#include <math.h>
#include <type_traits>

typedef __bf16 bf16x8 __attribute__((ext_vector_type(8)));
typedef float f32x4 __attribute__((ext_vector_type(4)));
typedef unsigned int u32x4 __attribute__((ext_vector_type(4)));

#define B_TOT 16384
#define D_TOT 64
#define R_TOT 63
#define H_TOT 256
#define PK_TOT 24
#define PI_F 3.14159265358979323846f

// ws layout: W1F fragments then W2F fragments (u32 units)
#define W2F_BASE_U32 1032192u
#define WS_NEED 6193152u

#define MFMA16(a, b, c) __builtin_amdgcn_mfma_f32_16x16x32_bf16((a), (b), (c), 0, 0, 0)

__device__ __forceinline__ unsigned short bf16_rtne(float f) {
    unsigned u = __float_as_uint(f);
    unsigned rr = u + 0x7FFFu + ((u >> 16) & 1u);
    return (unsigned short)(rr >> 16);
}

// one v_cvt_pk_bf16_f32: packs rtne(a) | rtne(b)<<16 (no builtin on gfx950)
__device__ __forceinline__ unsigned cvt_pk_bf16(float a, float b) {
    unsigned r;
    asm("v_cvt_pk_bf16_f32 %0, %1, %2" : "=v"(r) : "v"(a), "v"(b));
    return r;
}

// split 4 f32 -> hi plane (truncated bf16 x4) + lo plane (rtne residual x4)
__device__ __forceinline__ void split4(const float* v, uint2& hi, uint2& lo) {
    unsigned u0 = __float_as_uint(v[0]), u1 = __float_as_uint(v[1]);
    unsigned u2 = __float_as_uint(v[2]), u3 = __float_as_uint(v[3]);
    hi.x = __builtin_amdgcn_perm(u1, u0, 0x07060302u);   // {u1.hi16, u0.hi16}
    hi.y = __builtin_amdgcn_perm(u3, u2, 0x07060302u);
    float r0 = v[0] - __uint_as_float(u0 & 0xFFFF0000u);
    float r1 = v[1] - __uint_as_float(u1 & 0xFFFF0000u);
    float r2 = v[2] - __uint_as_float(u2 & 0xFFFF0000u);
    float r3 = v[3] - __uint_as_float(u3 & 0xFFFF0000u);
    lo.x = cvt_pk_bf16(r0, r1);
    lo.y = cvt_pk_bf16(r2, r3);
}

__global__ void init_out_kernel(float* __restrict__ out) {
    int b = blockIdx.x * 256 + threadIdx.x;
    if (b < B_TOT) {
        out[(size_t)b * D_TOT] = 0.0f;            // x[:,0] = 0
        out[(size_t)B_TOT * D_TOT + b] = 0.0f;    // log_det = 0
    }
}

// ---------------- prep: weights -> split-bf16 MFMA fragments in ws ----------------
// Bias trick: b1[r] is stored in the free padded K-row (d=31 for r<=30, d=63 for r>=31);
// the main kernel forces the staged z at that row to 1.0, so GEMM1 emits z*W1m + b1.
__global__ void prep_weights(const float* __restrict__ W1,
                             const float* __restrict__ b1,
                             const float* __restrict__ W2,
                             unsigned int* __restrict__ wsf)
{
    int gid = blockIdx.x * 256 + threadIdx.x;
    if (gid >= 193536) return;
    float v[8];
    unsigned int* dst;
    if (gid < 129024) {
        int lane = gid & 63;
        int q = gid >> 6;
        int t = q & 1; q >>= 1;
        int nt = q & 15; int r = q >> 4;
        int n  = (nt << 4) + (lane & 15);
        int kb = (t << 5) + ((lane >> 4) << 3);
        int bias_d = (r <= 30) ? 31 : 63;
        #pragma unroll
        for (int j = 0; j < 8; ++j) {
            int d = kb + j;
            v[j] = (d <= r) ? W1[(size_t)(r * 64 + d) * 256 + n]
                 : (d == bias_d ? b1[(size_t)r * 256 + n] : 0.0f);
        }
        int frag = ((r * 16 + nt) * 2 + t) * 2;
        dst = wsf + ((size_t)frag * 64 + lane) * 4;
    } else {
        int g2 = gid - 129024;
        int lane = g2 & 63;
        int q = g2 >> 6;
        int ks = q & 7; q >>= 3;
        int nt = q & 1; int r = q >> 1;
        int n  = (nt << 4) + (lane & 15);
        int kb = (ks << 5) + ((lane >> 4) << 3);
        #pragma unroll
        for (int j = 0; j < 8; ++j) {
            int k = kb + j;
            v[j] = (n < PK_TOT) ? W2[(size_t)(r * 256 + k) * PK_TOT + n] : 0.0f;
        }
        int frag = ((r * 2 + nt) * 8 + ks) * 2;
        dst = wsf + W2F_BASE_U32 + ((size_t)frag * 64 + lane) * 4;
    }
    unsigned hw[4], lw[4];
    #pragma unroll
    for (int i = 0; i < 4; ++i) {
        float a = v[2 * i], b = v[2 * i + 1];
        unsigned ua = __float_as_uint(a), ub = __float_as_uint(b);
        float ra = a - __uint_as_float(ua & 0xFFFF0000u);
        float rb = b - __uint_as_float(ub & 0xFFFF0000u);
        hw[i] = (ua >> 16) | (ub & 0xFFFF0000u);
        lw[i] = (unsigned)bf16_rtne(ra) | ((unsigned)bf16_rtne(rb) << 16);
    }
    *reinterpret_cast<u32x4*>(dst)       = u32x4{hw[0], hw[1], hw[2], hw[3]};
    *reinterpret_cast<u32x4*>(dst + 256) = u32x4{lw[0], lw[1], lw[2], lw[3]};
}

// ---------------- main MFMA kernel: block = 64 batches x one r, 4 waves ----------------
// 32 KB LDS; launch_bounds min-waves=3 (known no-spill; (256,5) forced unified
// VGPR/AGPR cap ~102 -> accumulators spilled to scratch -> 2.1 GB HBM traffic, 500us).
// h is stored single-plane bf16 (RTNE); z/W1 and W2 keep hi/lo split.
__global__ __launch_bounds__(256, 3) void flow_mfma(
    const float* __restrict__ z, const unsigned int* __restrict__ wsf,
    const float* __restrict__ b2, float* __restrict__ out)
{
    const int r   = blockIdx.y;
    const int b0  = blockIdx.x << 6;
    const int tid = threadIdx.x;
    const int w   = tid >> 6;
    const int l   = tid & 63;
    const int l15 = l & 15, l4 = l >> 4, key = l & 7;

    __shared__ __align__(16) unsigned char sm[32768];

    // ---- stage z split (hi trunc / lo rtne); bias row forced to 1.0 ----
    {
        const int m  = tid >> 2;
        const int dq = (tid & 3) << 4;
        const float* zp = z + (size_t)(b0 + m) * 64 + dq;
        const int mkey = m & 7;
        const int bias_d = (r <= 30) ? 31 : 63;
        const int rel = bias_d - dq;            // in [0,16) only for the owning thread
        #pragma unroll
        for (int qq = 0; qq < 4; ++qq) {
            float4 val = *reinterpret_cast<const float4*>(zp + (qq << 2));
            int d0 = dq + (qq << 2);
            float vv[4] = {val.x, val.y, val.z, val.w};
            if ((rel >> 2) == qq) vv[rel & 3] = 1.0f;   // bias row -> 1.0 (exact split)
            uint2 hi, lo;
            split4(vv, hi, lo);
            int off = (m << 7) + ((((d0 >> 3)) ^ mkey) << 4) + (((d0 >> 2) & 1) << 3);
            *reinterpret_cast<uint2*>(sm + off) = hi;
            *reinterpret_cast<uint2*>(sm + 8192 + off) = lo;
        }
    }
    __syncthreads();

    // ---- GEMM1 (output-transposed): D1[n][m] = sum_d W1m[d][n] * z[m][d] (+ b1 via bias row) ----
    f32x4 acc1[4][4];     // [ntl][mt]
    #pragma unroll
    for (int a = 0; a < 4; ++a)
        #pragma unroll
        for (int b = 0; b < 4; ++b) acc1[a][b] = f32x4{0.f, 0.f, 0.f, 0.f};

    auto run_gemm1 = [&](auto FULLC) {
        constexpr bool FULL = decltype(FULLC)::value;
        constexpr int NT = FULL ? 2 : 1;
        bf16x8 zf[4][NT][2];   // [mt][t][plane]
        #pragma unroll
        for (int mt = 0; mt < 4; ++mt)
            #pragma unroll
            for (int t = 0; t < NT; ++t) {
                int m = (mt << 4) + l15;
                int off = (m << 7) + ((((t << 2) + l4) ^ key) << 4);
                zf[mt][t][0] = __builtin_bit_cast(bf16x8, *reinterpret_cast<u32x4*>(sm + off));
                zf[mt][t][1] = __builtin_bit_cast(bf16x8, *reinterpret_cast<u32x4*>(sm + 8192 + off));
            }
        const unsigned int* w1b = wsf + (size_t)((r * 16 + (w << 2)) * 4) * 256 + (l << 2);
        #pragma unroll
        for (int ntl = 0; ntl < 4; ++ntl) {
            bf16x8 af[NT][2];
            #pragma unroll
            for (int t = 0; t < NT; ++t)
                #pragma unroll
                for (int pl = 0; pl < 2; ++pl)
                    af[t][pl] = __builtin_bit_cast(bf16x8,
                        *reinterpret_cast<const u32x4*>(w1b + ((ntl * 4 + t * 2 + pl) << 8)));
            #pragma unroll
            for (int t = 0; t < NT; ++t) {
                #pragma unroll
                for (int mt = 0; mt < 4; ++mt)
                    acc1[ntl][mt] = MFMA16(af[t][0], zf[mt][t][0], acc1[ntl][mt]);
                #pragma unroll
                for (int mt = 0; mt < 4; ++mt)
                    acc1[ntl][mt] = MFMA16(af[t][0], zf[mt][t][1], acc1[ntl][mt]);
                #pragma unroll
                for (int mt = 0; mt < 4; ++mt)
                    acc1[ntl][mt] = MFMA16(af[t][1], zf[mt][t][0], acc1[ntl][mt]);
            }
        }
    };
    if (r >= 31) run_gemm1(std::true_type{});
    else         run_gemm1(std::false_type{});

    // relu + RTNE bf16 (single plane), write this wave's 64 h-columns into the half-tile
    auto write_h = [&]() {
        #pragma unroll
        for (int ntl = 0; ntl < 4; ++ntl) {
            #pragma unroll
            for (int mt = 0; mt < 4; ++mt) {
                float vv[4];
                #pragma unroll
                for (int i = 0; i < 4; ++i)
                    vv[i] = fmaxf(acc1[ntl][mt][i], 0.0f);
                uint2 hi;
                hi.x = cvt_pk_bf16(vv[0], vv[1]);
                hi.y = cvt_pk_bf16(vv[2], vv[3]);
                int m   = (mt << 4) + l15;
                int gl  = ((w & 1) << 3) + (ntl << 1) + (l4 >> 1);
                int off = (m << 8) + ((gl ^ key) << 4) + ((l4 & 1) << 3);
                *reinterpret_cast<uint2*>(sm + 16384 + off) = hi;
            }
        }
    };

    f32x4 acc2[2][4];     // [nt2][mt]  D2[n][m] = sum_k W2[k][n] h[m][k]
    #pragma unroll
    for (int a = 0; a < 2; ++a)
        #pragma unroll
        for (int b = 0; b < 4; ++b) acc2[a][b] = f32x4{0.f, 0.f, 0.f, 0.f};

    const unsigned int* w2b = wsf + W2F_BASE_U32 + (size_t)(r * 32) * 256 + (l << 2);
    auto gemm2 = [&](int p) {
        const int ks = (p << 2) + w;   // wave's global k-step (32 k each)
        bf16x8 wf[2][2];
        #pragma unroll
        for (int nt2 = 0; nt2 < 2; ++nt2)
            #pragma unroll
            for (int pl = 0; pl < 2; ++pl)
                wf[nt2][pl] = __builtin_bit_cast(bf16x8,
                    *reinterpret_cast<const u32x4*>(w2b + ((nt2 * 16 + ks * 2 + pl) << 8)));
        bf16x8 hfr[4];
        #pragma unroll
        for (int mt = 0; mt < 4; ++mt) {
            int m   = (mt << 4) + l15;
            int off = (m << 8) + ((((w << 2) + l4) ^ key) << 4);
            hfr[mt] = __builtin_bit_cast(bf16x8, *reinterpret_cast<u32x4*>(sm + 16384 + off));
        }
        #pragma unroll
        for (int nt2 = 0; nt2 < 2; ++nt2)
            #pragma unroll
            for (int mt = 0; mt < 4; ++mt)
                acc2[nt2][mt] = MFMA16(wf[nt2][0], hfr[mt], acc2[nt2][mt]);
        #pragma unroll
        for (int nt2 = 0; nt2 < 2; ++nt2)
            #pragma unroll
            for (int mt = 0; mt < 4; ++mt)
                acc2[nt2][mt] = MFMA16(wf[nt2][1], hfr[mt], acc2[nt2][mt]);
    };

    if (w < 2) write_h();       // waves 0,1 own h-cols 0..127
    __syncthreads();
    gemm2(0);                   // k = 0..127
    __syncthreads();
    if (w >= 2) write_h();      // h-cols 128..255 overwrite the half-tile
    __syncthreads();
    gemm2(1);                   // k = 128..255

    // ---- cross-wave reduce of raw via LDS (aliases dead z region) ----
    auto part_off = [&](int ph, int nt2, int mt) -> int {
        int m = (mt << 4) + l15;
        return (((ph << 6) + m) << 7) + ((((nt2 << 2) + l4) ^ key) << 4);
    };
    if (w < 2) {
        #pragma unroll
        for (int nt2 = 0; nt2 < 2; ++nt2)
            #pragma unroll
            for (int mt = 0; mt < 4; ++mt)
                *reinterpret_cast<f32x4*>(sm + part_off(w, nt2, mt)) = acc2[nt2][mt];
    }
    __syncthreads();
    if (w >= 2) {
        #pragma unroll
        for (int nt2 = 0; nt2 < 2; ++nt2)
            #pragma unroll
            for (int mt = 0; mt < 4; ++mt) {
                f32x4* p = reinterpret_cast<f32x4*>(sm + part_off(w - 2, nt2, mt));
                *p = *p + acc2[nt2][mt];
            }
    }
    __syncthreads();

    // ---- flow epilogue (fast transcendentals) ----
    #pragma unroll
    for (int mh = 0; mh < 2; ++mh) {
        const int m  = (mh << 5) + (tid >> 3);
        const int j  = tid & 7;
        const int mk = m & 7;
        float ra = b2[(size_t)r * 24 + j];
        float rb = b2[(size_t)r * 24 + 8 + j];
        float rr = b2[(size_t)r * 24 + 16 + j];
        #pragma unroll
        for (int ph = 0; ph < 2; ++ph) {
            const int base = (((ph << 6) + m) << 7);
            const int sub  = (j & 3) << 2;
            ra += *reinterpret_cast<float*>(sm + base + ((((j) >> 2) ^ mk) << 4) + sub);
            rb += *reinterpret_cast<float*>(sm + base + ((((8 + j) >> 2) ^ mk) << 4) + sub);
            rr += *reinterpret_cast<float*>(sm + base + ((((16 + j) >> 2) ^ mk) << 4) + sub);
        }
        float zi = z[(size_t)(b0 + m) * 64 + r + 1];
        // tan((zi - pi)/2) == -cos(zi/2)/sin(zi/2); clamp to avoid inf^2/inf^2 NaN at zi=0
        float s, c;
        __sincosf(zi * 0.5f, &s, &c);
        float t = -c * __builtin_amdgcn_rcpf(s);
        t = fminf(fmaxf(t, -1e8f), 1e8f);
        float al = __expf(ra);
        float g  = fmaf(al, t, rb);
        float X  = 2.0f * atanf(g) + PI_F;
        float dv = al * fmaf(t, t, 1.0f) * __builtin_amdgcn_rcpf(fmaf(g, g, 1.0f));
        float mx = rr;
        mx = fmaxf(mx, __shfl_xor(mx, 1));
        mx = fmaxf(mx, __shfl_xor(mx, 2));
        mx = fmaxf(mx, __shfl_xor(mx, 4));
        float e = __expf(rr - mx);
        float se = e, sx = e * X, sd = e * dv;
        se += __shfl_xor(se, 1); se += __shfl_xor(se, 2); se += __shfl_xor(se, 4);
        sx += __shfl_xor(sx, 1); sx += __shfl_xor(sx, 2); sx += __shfl_xor(sx, 4);
        sd += __shfl_xor(sd, 1); sd += __shfl_xor(sd, 2); sd += __shfl_xor(sd, 4);
        if (j == 0) {
            int gb = b0 + m;
            float rse = __builtin_amdgcn_rcpf(se);
            out[(size_t)gb * D_TOT + r + 1] = sx * rse;
            atomicAdd(&out[(size_t)B_TOT * D_TOT + gb], __logf(sd * rse));
        }
    }
}

// ---------------- fp32 fallback (round-1 kernel, known-correct) ----------------
__global__ __launch_bounds__(256, 2) void flow_fp32(
    const float* __restrict__ z,  const float* __restrict__ W1,
    const float* __restrict__ b1, const float* __restrict__ W2,
    const float* __restrict__ b2, float* __restrict__ out)
{
    const int r   = blockIdx.y;
    const int b0  = blockIdx.x * 32;
    const int tid = threadIdx.x;

    __shared__ float smem[16384];
    float* z_t  = smem;
    float* h_s  = smem + 2048;
    float* w2t  = smem + 2048 + 8192;
    float* part = w2t;

    #pragma unroll
    for (int it = 0; it < 2; ++it) {
        int idx4 = it * 256 + tid;
        int brow = idx4 >> 4;
        int dq   = (idx4 & 15) << 2;
        float4 v = *reinterpret_cast<const float4*>(&z[(size_t)(b0 + brow) * D_TOT + dq]);
        z_t[(dq + 0) * 32 + brow] = v.x;
        z_t[(dq + 1) * 32 + brow] = v.y;
        z_t[(dq + 2) * 32 + brow] = v.z;
        z_t[(dq + 3) * 32 + brow] = v.w;
    }
    #pragma unroll
    for (int it = 0; it < 6; ++it) {
        int idx4 = it * 256 + tid;
        int k  = idx4 / 6;
        int pq = (idx4 - k * 6) << 2;
        float4 v = *reinterpret_cast<const float4*>(&W2[(size_t)(r * H_TOT + k) * PK_TOT + pq]);
        int gk = k >> 2, kq = k & 3;
        w2t[(pq + 0) * 256 + (((gk) ^ ((pq + 0) & 7)) << 2) + kq] = v.x;
        w2t[(pq + 1) * 256 + (((gk) ^ ((pq + 1) & 7)) << 2) + kq] = v.y;
        w2t[(pq + 2) * 256 + (((gk) ^ ((pq + 2) & 7)) << 2) + kq] = v.z;
        w2t[(pq + 3) * 256 + (((gk) ^ ((pq + 3) & 7)) << 2) + kq] = v.w;
    }
    __syncthreads();

    const int rg = tid & 15;
    const int cg = tid >> 4;
    float acc[2][16];
    #pragma unroll
    for (int j = 0; j < 2; ++j)
        #pragma unroll
        for (int i = 0; i < 16; ++i) acc[j][i] = 0.0f;

    const float* w1p = W1 + (size_t)(r * D_TOT) * H_TOT + (cg << 4);
    #pragma unroll 4
    for (int d = 0; d <= r; ++d) {
        float2 zv = *reinterpret_cast<const float2*>(&z_t[d * 32 + (rg << 1)]);
        const float* wrow = w1p + (size_t)d * H_TOT;
        float wv[16];
        *reinterpret_cast<float4*>(&wv[0])  = *reinterpret_cast<const float4*>(wrow + 0);
        *reinterpret_cast<float4*>(&wv[4])  = *reinterpret_cast<const float4*>(wrow + 4);
        *reinterpret_cast<float4*>(&wv[8])  = *reinterpret_cast<const float4*>(wrow + 8);
        *reinterpret_cast<float4*>(&wv[12]) = *reinterpret_cast<const float4*>(wrow + 12);
        #pragma unroll
        for (int i = 0; i < 16; ++i) {
            acc[0][i] = fmaf(zv.x, wv[i], acc[0][i]);
            acc[1][i] = fmaf(zv.y, wv[i], acc[1][i]);
        }
    }
    {
        const int key = (rg >> 1) & 7;
        #pragma unroll
        for (int gi = 0; gi < 4; ++gi) {
            float4 bv = *reinterpret_cast<const float4*>(&b1[(size_t)r * H_TOT + (cg << 4) + (gi << 2)]);
            #pragma unroll
            for (int j = 0; j < 2; ++j) {
                float4 v;
                v.x = fmaxf(acc[j][4 * gi + 0] + bv.x, 0.0f);
                v.y = fmaxf(acc[j][4 * gi + 1] + bv.y, 0.0f);
                v.z = fmaxf(acc[j][4 * gi + 2] + bv.z, 0.0f);
                v.w = fmaxf(acc[j][4 * gi + 3] + bv.w, 0.0f);
                int bb = (rg << 1) + j;
                int g  = ((cg << 2) + gi) ^ key;
                *reinterpret_cast<float4*>(&h_s[bb * 256 + (g << 2)]) = v;
            }
        }
    }
    __syncthreads();

    const int wv_ = tid >> 6;
    const int ln  = tid & 63;
    const int bq  = ln & 7;
    const int pg  = ln >> 3;
    float acc2[4][3];
    #pragma unroll
    for (int j = 0; j < 4; ++j)
        #pragma unroll
        for (int i = 0; i < 3; ++i) acc2[j][i] = 0.0f;

    #pragma unroll
    for (int c = 0; c < 8; ++c) {
        int k0  = (wv_ << 6) + (c << 3);
        int gk0 = k0 >> 2;
        float w2r[3][8], hr[4][8];
        #pragma unroll
        for (int i = 0; i < 3; ++i) {
            int p = 3 * pg + i, pk = p & 7;
            *reinterpret_cast<float4*>(&w2r[i][0]) =
                *reinterpret_cast<const float4*>(&w2t[p * 256 + (((gk0 + 0) ^ pk) << 2)]);
            *reinterpret_cast<float4*>(&w2r[i][4]) =
                *reinterpret_cast<const float4*>(&w2t[p * 256 + (((gk0 + 1) ^ pk) << 2)]);
        }
        #pragma unroll
        for (int j = 0; j < 4; ++j) {
            int bb = 4 * bq + j;
            *reinterpret_cast<float4*>(&hr[j][0]) =
                *reinterpret_cast<const float4*>(&h_s[bb * 256 + (((gk0 + 0) ^ bq) << 2)]);
            *reinterpret_cast<float4*>(&hr[j][4]) =
                *reinterpret_cast<const float4*>(&h_s[bb * 256 + (((gk0 + 1) ^ bq) << 2)]);
        }
        #pragma unroll
        for (int kk = 0; kk < 8; ++kk)
            #pragma unroll
            for (int j = 0; j < 4; ++j)
                #pragma unroll
                for (int i = 0; i < 3; ++i)
                    acc2[j][i] = fmaf(hr[j][kk], w2r[i][kk], acc2[j][i]);
    }
    __syncthreads();
    #pragma unroll
    for (int j = 0; j < 4; ++j)
        #pragma unroll
        for (int i = 0; i < 3; ++i)
            part[((wv_ << 5) + 4 * bq + j) * PK_TOT + 3 * pg + i] = acc2[j][i];
    __syncthreads();

    {
        const int eb = tid >> 3;
        const int ej = tid & 7;
        float rawa = b2[(size_t)r * PK_TOT + ej];
        float rawb = b2[(size_t)r * PK_TOT + 8 + ej];
        float rawr = b2[(size_t)r * PK_TOT + 16 + ej];
        #pragma unroll
        for (int w = 0; w < 4; ++w) {
            rawa += part[((w << 5) + eb) * PK_TOT + ej];
            rawb += part[((w << 5) + eb) * PK_TOT + 8 + ej];
            rawr += part[((w << 5) + eb) * PK_TOT + 16 + ej];
        }
        float zi = z_t[(r + 1) * 32 + eb];
        float t  = tanf((zi - PI_F) * 0.5f);
        float al = expf(rawa);
        float g  = fmaf(al, t, rawb);
        float X  = 2.0f * atanf(g) + PI_F;
        float dv = al * (1.0f + t * t) / (1.0f + g * g);
        float m = rawr;
        m = fmaxf(m, __shfl_xor(m, 1));
        m = fmaxf(m, __shfl_xor(m, 2));
        m = fmaxf(m, __shfl_xor(m, 4));
        float e  = expf(rawr - m);
        float se = e, sx = e * X, sd = e * dv;
        se += __shfl_xor(se, 1); se += __shfl_xor(se, 2); se += __shfl_xor(se, 4);
        sx += __shfl_xor(sx, 1); sx += __shfl_xor(sx, 2); sx += __shfl_xor(sx, 4);
        sd += __shfl_xor(sd, 1); sd += __shfl_xor(sd, 2); sd += __shfl_xor(sd, 4);
        if (ej == 0) {
            int gb = b0 + eb;
            out[(size_t)gb * D_TOT + (r + 1)] = sx / se;
            atomicAdd(&out[(size_t)B_TOT * D_TOT + gb], logf(sd / se));
        }
    }
}

extern "C" void kernel_launch(void* const* d_in, const int* in_sizes, int n_in,
                              void* d_out, int out_size, void* d_ws, size_t ws_size,
                              hipStream_t stream) {
    const float* z  = (const float*)d_in[0];
    const float* W1 = (const float*)d_in[1];
    const float* b1 = (const float*)d_in[2];
    const float* W2 = (const float*)d_in[3];
    const float* b2 = (const float*)d_in[4];
    float* out = (float*)d_out;

    init_out_kernel<<<dim3(B_TOT / 256), dim3(256), 0, stream>>>(out);
    if (ws_size >= (size_t)WS_NEED) {
        prep_weights<<<dim3(756), dim3(256), 0, stream>>>(W1, b1, W2, (unsigned int*)d_ws);
        flow_mfma<<<dim3(B_TOT / 64, R_TOT), dim3(256), 0, stream>>>(
            z, (const unsigned int*)d_ws, b2, out);
    } else {
        flow_fp32<<<dim3(B_TOT / 32, R_TOT), dim3(256), 0, stream>>>(z, W1, b1, W2, b2, out);
    }
}

// Round 7
// 143.208 us; speedup vs baseline: 3.4928x; 1.0791x over previous
//
#include <hip/hip_runtime.h>
#include <math.h>
#include <type_traits>

typedef __bf16 bf16x8 __attribute__((ext_vector_type(8)));
typedef float f32x4 __attribute__((ext_vector_type(4)));
typedef unsigned int u32x4 __attribute__((ext_vector_type(4)));

#define B_TOT 16384
#define D_TOT 64
#define R_TOT 63
#define H_TOT 256
#define PK_TOT 24
#define PI_F 3.14159265358979323846f

// ws layout (u32 units): W1F frags [((r*16+nt)*2+t)] then W2F frags [(r*2+nt2)*8+ks]
// all single-plane RTNE bf16.
#define W2F_BASE_U32 516096u
#define WS_NEED 3096576u

#define MFMA16(a, b, c) __builtin_amdgcn_mfma_f32_16x16x32_bf16((a), (b), (c), 0, 0, 0)

__device__ __forceinline__ unsigned short bf16_rtne(float f) {
    unsigned u = __float_as_uint(f);
    unsigned rr = u + 0x7FFFu + ((u >> 16) & 1u);
    return (unsigned short)(rr >> 16);
}

// one v_cvt_pk_bf16_f32: packs rtne(a) | rtne(b)<<16 (no builtin on gfx950)
__device__ __forceinline__ unsigned cvt_pk_bf16(float a, float b) {
    unsigned r;
    asm("v_cvt_pk_bf16_f32 %0, %1, %2" : "=v"(r) : "v"(a), "v"(b));
    return r;
}

// split 4 f32 -> hi plane (truncated bf16 x4) + lo plane (rtne residual x4)
__device__ __forceinline__ void split4(const float* v, uint2& hi, uint2& lo) {
    unsigned u0 = __float_as_uint(v[0]), u1 = __float_as_uint(v[1]);
    unsigned u2 = __float_as_uint(v[2]), u3 = __float_as_uint(v[3]);
    hi.x = __builtin_amdgcn_perm(u1, u0, 0x07060302u);   // {u1.hi16, u0.hi16}
    hi.y = __builtin_amdgcn_perm(u3, u2, 0x07060302u);
    float r0 = v[0] - __uint_as_float(u0 & 0xFFFF0000u);
    float r1 = v[1] - __uint_as_float(u1 & 0xFFFF0000u);
    float r2 = v[2] - __uint_as_float(u2 & 0xFFFF0000u);
    float r3 = v[3] - __uint_as_float(u3 & 0xFFFF0000u);
    lo.x = cvt_pk_bf16(r0, r1);
    lo.y = cvt_pk_bf16(r2, r3);
}

__global__ void init_out_kernel(float* __restrict__ out) {
    int b = blockIdx.x * 256 + threadIdx.x;
    if (b < B_TOT) {
        out[(size_t)b * D_TOT] = 0.0f;            // x[:,0] = 0
        out[(size_t)B_TOT * D_TOT + b] = 0.0f;    // log_det = 0
    }
}

// ---------------- prep: weights -> single-plane RTNE bf16 MFMA fragments ----------------
// Bias trick: b1[r] in free padded K-row (d=31 for r<=30, d=63 for r>=31);
// main kernel forces staged z at that row to 1.0.
__global__ void prep_weights(const float* __restrict__ W1,
                             const float* __restrict__ b1,
                             const float* __restrict__ W2,
                             unsigned int* __restrict__ wsf)
{
    int gid = blockIdx.x * 256 + threadIdx.x;
    if (gid >= 193536) return;
    float v[8];
    unsigned int* dst;
    if (gid < 129024) {
        int lane = gid & 63;
        int q = gid >> 6;                  // frag idx 0..2015 = ((r*16+nt)*2+t)
        int t = q & 1; int qq = q >> 1;
        int nt = qq & 15; int r = qq >> 4;
        int n  = (nt << 4) + (lane & 15);
        int kb = (t << 5) + ((lane >> 4) << 3);
        int bias_d = (r <= 30) ? 31 : 63;
        #pragma unroll
        for (int j = 0; j < 8; ++j) {
            int d = kb + j;
            v[j] = (d <= r) ? W1[(size_t)(r * 64 + d) * 256 + n]
                 : (d == bias_d ? b1[(size_t)r * 256 + n] : 0.0f);
        }
        dst = wsf + (size_t)q * 256 + ((unsigned)lane << 2);
    } else {
        int g2 = gid - 129024;
        int lane = g2 & 63;
        int q = g2 >> 6;                   // frag idx 0..1007 = (r*2+nt)*8+ks
        int ks = q & 7; int qq = q >> 3;
        int nt = qq & 1; int r = qq >> 1;
        int n  = (nt << 4) + (lane & 15);
        int kb = (ks << 5) + ((lane >> 4) << 3);
        #pragma unroll
        for (int j = 0; j < 8; ++j) {
            int k = kb + j;
            v[j] = (n < PK_TOT) ? W2[(size_t)(r * 256 + k) * PK_TOT + n] : 0.0f;
        }
        dst = wsf + W2F_BASE_U32 + (size_t)q * 256 + ((unsigned)lane << 2);
    }
    unsigned hw[4];
    #pragma unroll
    for (int i = 0; i < 4; ++i)
        hw[i] = (unsigned)bf16_rtne(v[2 * i]) | ((unsigned)bf16_rtne(v[2 * i + 1]) << 16);
    *reinterpret_cast<u32x4*>(dst) = u32x4{hw[0], hw[1], hw[2], hw[3]};
}

// ---------------- main MFMA kernel: block = 64 batches x one r, 4 waves ----------------
// m-split phasing: two batch-halves of 32; per half all waves compute GEMM1
// (acc1 = 32 AGPR), write full-K h tile [32][256]bf16 (16KB), gemm2 full-K
// k-split (acc2 = 16 AGPR), partials alias h region, epilogue. Peak liveness
// ~80 combined regs -> (256,5): 5 blocks/CU (LDS 32KB caps at 5 too).
__global__ __launch_bounds__(256, 5) void flow_mfma(
    const float* __restrict__ z, const unsigned int* __restrict__ wsf,
    const float* __restrict__ b2, float* __restrict__ out)
{
    const int r   = blockIdx.y;
    const int b0  = blockIdx.x << 6;
    const int tid = threadIdx.x;
    const int w   = tid >> 6;
    const int l   = tid & 63;
    const int l15 = l & 15, l4 = l >> 4, key = l & 7;

    __shared__ __align__(16) unsigned char sm[32768];

    // ---- stage z split (hi trunc / lo rtne) for all 64 batches; bias row -> 1.0 ----
    {
        const int m  = tid >> 2;
        const int dq = (tid & 3) << 4;
        const float* zp = z + (size_t)(b0 + m) * 64 + dq;
        const int mkey = m & 7;
        const int bias_d = (r <= 30) ? 31 : 63;
        const int rel = bias_d - dq;
        #pragma unroll
        for (int qq = 0; qq < 4; ++qq) {
            float4 val = *reinterpret_cast<const float4*>(zp + (qq << 2));
            int d0 = dq + (qq << 2);
            float vv[4] = {val.x, val.y, val.z, val.w};
            if ((rel >> 2) == qq) vv[rel & 3] = 1.0f;
            uint2 hi, lo;
            split4(vv, hi, lo);
            int off = (m << 7) + ((((d0 >> 3)) ^ mkey) << 4) + (((d0 >> 2) & 1) << 3);
            *reinterpret_cast<uint2*>(sm + off) = hi;
            *reinterpret_cast<uint2*>(sm + 8192 + off) = lo;
        }
    }
    __syncthreads();

    const unsigned int* w1b = wsf + (size_t)((r * 16 + (w << 2)) * 2) * 256 + (l << 2);
    const unsigned int* w2b = wsf + W2F_BASE_U32 + (size_t)(r * 16) * 256 + (l << 2);

    #pragma unroll 1
    for (int mh = 0; mh < 2; ++mh) {
        // ---- GEMM1 for batches mh*32..+32: D1[n][m] = sum_d W1m[d][n]*z[m][d] ----
        f32x4 acc1[4][2];
        #pragma unroll
        for (int a = 0; a < 4; ++a)
            #pragma unroll
            for (int b = 0; b < 2; ++b) acc1[a][b] = f32x4{0.f, 0.f, 0.f, 0.f};

        auto run_gemm1 = [&](auto FULLC) {
            constexpr int NT = decltype(FULLC)::value ? 2 : 1;
            #pragma unroll
            for (int t = 0; t < NT; ++t) {
                bf16x8 zf[2][2];   // [mt][plane] for this t
                #pragma unroll
                for (int mt = 0; mt < 2; ++mt) {
                    int m = (mh << 5) + (mt << 4) + l15;
                    int off = (m << 7) + ((((t << 2) + l4) ^ key) << 4);
                    zf[mt][0] = __builtin_bit_cast(bf16x8, *reinterpret_cast<u32x4*>(sm + off));
                    zf[mt][1] = __builtin_bit_cast(bf16x8, *reinterpret_cast<u32x4*>(sm + 8192 + off));
                }
                #pragma unroll
                for (int ntl = 0; ntl < 4; ++ntl) {
                    bf16x8 af = __builtin_bit_cast(bf16x8,
                        *reinterpret_cast<const u32x4*>(w1b + (((ntl << 1) + t) << 8)));
                    #pragma unroll
                    for (int mt = 0; mt < 2; ++mt)
                        acc1[ntl][mt] = MFMA16(af, zf[mt][0], acc1[ntl][mt]);
                    #pragma unroll
                    for (int mt = 0; mt < 2; ++mt)
                        acc1[ntl][mt] = MFMA16(af, zf[mt][1], acc1[ntl][mt]);
                }
            }
        };
        if (r >= 31) run_gemm1(std::true_type{});
        else         run_gemm1(std::false_type{});

        // ---- relu + RTNE bf16, write h tile [32][256]bf16 at 16384 (row 512B) ----
        #pragma unroll
        for (int ntl = 0; ntl < 4; ++ntl) {
            #pragma unroll
            for (int mt = 0; mt < 2; ++mt) {
                float v0 = fmaxf(acc1[ntl][mt][0], 0.0f);
                float v1 = fmaxf(acc1[ntl][mt][1], 0.0f);
                float v2 = fmaxf(acc1[ntl][mt][2], 0.0f);
                float v3 = fmaxf(acc1[ntl][mt][3], 0.0f);
                uint2 hv;
                hv.x = cvt_pk_bf16(v0, v1);
                hv.y = cvt_pk_bf16(v2, v3);
                int mloc = (mt << 4) + l15;
                int g    = (w << 3) + (ntl << 1) + (l4 >> 1);           // granule 0..31
                int off  = 16384 + (mloc << 9)
                         + (((g & 24) | ((g ^ key) & 7)) << 4) + ((l4 & 1) << 3);
                *reinterpret_cast<uint2*>(sm + off) = hv;
            }
        }
        __syncthreads();

        // ---- gemm2 full-K, k-split: wave w covers k = w*64..w*64+63 ----
        f32x4 acc2[2][2];
        #pragma unroll
        for (int a = 0; a < 2; ++a)
            #pragma unroll
            for (int b = 0; b < 2; ++b) acc2[a][b] = f32x4{0.f, 0.f, 0.f, 0.f};

        #pragma unroll
        for (int kk = 0; kk < 2; ++kk) {
            const int ks = (w << 1) + kk;
            bf16x8 wf[2];
            #pragma unroll
            for (int nt2 = 0; nt2 < 2; ++nt2)
                wf[nt2] = __builtin_bit_cast(bf16x8,
                    *reinterpret_cast<const u32x4*>(w2b + (((nt2 << 3) + ks) << 8)));
            bf16x8 hfr[2];
            #pragma unroll
            for (int mt = 0; mt < 2; ++mt) {
                int mloc = (mt << 4) + l15;
                int g    = (ks << 2) + l4;
                int off  = 16384 + (mloc << 9)
                         + (((g & 24) | ((g ^ key) & 7)) << 4);
                hfr[mt] = __builtin_bit_cast(bf16x8, *reinterpret_cast<u32x4*>(sm + off));
            }
            #pragma unroll
            for (int nt2 = 0; nt2 < 2; ++nt2)
                #pragma unroll
                for (int mt = 0; mt < 2; ++mt)
                    acc2[nt2][mt] = MFMA16(wf[nt2], hfr[mt], acc2[nt2][mt]);
        }
        __syncthreads();   // h reads done; alias region as partials

        // ---- partials [4 waves][32 m][32 p-pad] f32 = 16KB over h region ----
        #pragma unroll
        for (int nt2 = 0; nt2 < 2; ++nt2)
            #pragma unroll
            for (int mt = 0; mt < 2; ++mt) {
                int row = (w << 5) + (mt << 4) + l15;
                int off = 16384 + (row << 7) + ((((nt2 << 2) + l4) ^ key) << 4);
                *reinterpret_cast<f32x4*>(sm + off) = acc2[nt2][mt];
            }
        __syncthreads();

        // ---- flow epilogue for this batch-half: thread = (mloc = tid>>3, j = tid&7) ----
        {
            const int mloc = tid >> 3;
            const int j    = tid & 7;
            const int mk   = mloc & 7;
            float ra = b2[(size_t)r * 24 + j];
            float rb = b2[(size_t)r * 24 + 8 + j];
            float rr = b2[(size_t)r * 24 + 16 + j];
            #pragma unroll
            for (int w4 = 0; w4 < 4; ++w4) {
                const int base = 16384 + (((w4 << 5) + mloc) << 7);
                const int sub  = (j & 3) << 2;
                ra += *reinterpret_cast<float*>(sm + base + ((((j) >> 2) ^ mk) << 4) + sub);
                rb += *reinterpret_cast<float*>(sm + base + (((2 + (j >> 2)) ^ mk) << 4) + sub);
                rr += *reinterpret_cast<float*>(sm + base + (((4 + (j >> 2)) ^ mk) << 4) + sub);
            }
            int gb = b0 + (mh << 5) + mloc;
            float zi = z[(size_t)gb * 64 + r + 1];
            // tan((zi-pi)/2) == -cos(zi/2)/sin(zi/2); clamp avoids inf^2/inf^2 NaN at zi=0
            float s, c;
            __sincosf(zi * 0.5f, &s, &c);
            float t = -c * __builtin_amdgcn_rcpf(s);
            t = fminf(fmaxf(t, -1e8f), 1e8f);
            float al = __expf(ra);
            float g  = fmaf(al, t, rb);
            float X  = 2.0f * atanf(g) + PI_F;
            float dv = al * fmaf(t, t, 1.0f) * __builtin_amdgcn_rcpf(fmaf(g, g, 1.0f));
            float mx = rr;
            mx = fmaxf(mx, __shfl_xor(mx, 1));
            mx = fmaxf(mx, __shfl_xor(mx, 2));
            mx = fmaxf(mx, __shfl_xor(mx, 4));
            float e = __expf(rr - mx);
            float se = e, sx = e * X, sd = e * dv;
            se += __shfl_xor(se, 1); se += __shfl_xor(se, 2); se += __shfl_xor(se, 4);
            sx += __shfl_xor(sx, 1); sx += __shfl_xor(sx, 2); sx += __shfl_xor(sx, 4);
            sd += __shfl_xor(sd, 1); sd += __shfl_xor(sd, 2); sd += __shfl_xor(sd, 4);
            if (j == 0) {
                float rse = __builtin_amdgcn_rcpf(se);
                out[(size_t)gb * D_TOT + r + 1] = sx * rse;
                atomicAdd(&out[(size_t)B_TOT * D_TOT + gb], __logf(sd * rse));
            }
        }
        __syncthreads();   // partial region reused as h tile next half
    }
}

// ---------------- fp32 fallback (round-1 kernel, known-correct) ----------------
__global__ __launch_bounds__(256, 2) void flow_fp32(
    const float* __restrict__ z,  const float* __restrict__ W1,
    const float* __restrict__ b1, const float* __restrict__ W2,
    const float* __restrict__ b2, float* __restrict__ out)
{
    const int r   = blockIdx.y;
    const int b0  = blockIdx.x * 32;
    const int tid = threadIdx.x;

    __shared__ float smem[16384];
    float* z_t  = smem;
    float* h_s  = smem + 2048;
    float* w2t  = smem + 2048 + 8192;
    float* part = w2t;

    #pragma unroll
    for (int it = 0; it < 2; ++it) {
        int idx4 = it * 256 + tid;
        int brow = idx4 >> 4;
        int dq   = (idx4 & 15) << 2;
        float4 v = *reinterpret_cast<const float4*>(&z[(size_t)(b0 + brow) * D_TOT + dq]);
        z_t[(dq + 0) * 32 + brow] = v.x;
        z_t[(dq + 1) * 32 + brow] = v.y;
        z_t[(dq + 2) * 32 + brow] = v.z;
        z_t[(dq + 3) * 32 + brow] = v.w;
    }
    #pragma unroll
    for (int it = 0; it < 6; ++it) {
        int idx4 = it * 256 + tid;
        int k  = idx4 / 6;
        int pq = (idx4 - k * 6) << 2;
        float4 v = *reinterpret_cast<const float4*>(&W2[(size_t)(r * H_TOT + k) * PK_TOT + pq]);
        int gk = k >> 2, kq = k & 3;
        w2t[(pq + 0) * 256 + (((gk) ^ ((pq + 0) & 7)) << 2) + kq] = v.x;
        w2t[(pq + 1) * 256 + (((gk) ^ ((pq + 1) & 7)) << 2) + kq] = v.y;
        w2t[(pq + 2) * 256 + (((gk) ^ ((pq + 2) & 7)) << 2) + kq] = v.z;
        w2t[(pq + 3) * 256 + (((gk) ^ ((pq + 3) & 7)) << 2) + kq] = v.w;
    }
    __syncthreads();

    const int rg = tid & 15;
    const int cg = tid >> 4;
    float acc[2][16];
    #pragma unroll
    for (int j = 0; j < 2; ++j)
        #pragma unroll
        for (int i = 0; i < 16; ++i) acc[j][i] = 0.0f;

    const float* w1p = W1 + (size_t)(r * D_TOT) * H_TOT + (cg << 4);
    #pragma unroll 4
    for (int d = 0; d <= r; ++d) {
        float2 zv = *reinterpret_cast<const float2*>(&z_t[d * 32 + (rg << 1)]);
        const float* wrow = w1p + (size_t)d * H_TOT;
        float wv[16];
        *reinterpret_cast<float4*>(&wv[0])  = *reinterpret_cast<const float4*>(wrow + 0);
        *reinterpret_cast<float4*>(&wv[4])  = *reinterpret_cast<const float4*>(wrow + 4);
        *reinterpret_cast<float4*>(&wv[8])  = *reinterpret_cast<const float4*>(wrow + 8);
        *reinterpret_cast<float4*>(&wv[12]) = *reinterpret_cast<const float4*>(wrow + 12);
        #pragma unroll
        for (int i = 0; i < 16; ++i) {
            acc[0][i] = fmaf(zv.x, wv[i], acc[0][i]);
            acc[1][i] = fmaf(zv.y, wv[i], acc[1][i]);
        }
    }
    {
        const int key = (rg >> 1) & 7;
        #pragma unroll
        for (int gi = 0; gi < 4; ++gi) {
            float4 bv = *reinterpret_cast<const float4*>(&b1[(size_t)r * H_TOT + (cg << 4) + (gi << 2)]);
            #pragma unroll
            for (int j = 0; j < 2; ++j) {
                float4 v;
                v.x = fmaxf(acc[j][4 * gi + 0] + bv.x, 0.0f);
                v.y = fmaxf(acc[j][4 * gi + 1] + bv.y, 0.0f);
                v.z = fmaxf(acc[j][4 * gi + 2] + bv.z, 0.0f);
                v.w = fmaxf(acc[j][4 * gi + 3] + bv.w, 0.0f);
                int bb = (rg << 1) + j;
                int g  = ((cg << 2) + gi) ^ key;
                *reinterpret_cast<float4*>(&h_s[bb * 256 + (g << 2)]) = v;
            }
        }
    }
    __syncthreads();

    const int wv_ = tid >> 6;
    const int ln  = tid & 63;
    const int bq  = ln & 7;
    const int pg  = ln >> 3;
    float acc2[4][3];
    #pragma unroll
    for (int j = 0; j < 4; ++j)
        #pragma unroll
        for (int i = 0; i < 3; ++i) acc2[j][i] = 0.0f;

    #pragma unroll
    for (int c = 0; c < 8; ++c) {
        int k0  = (wv_ << 6) + (c << 3);
        int gk0 = k0 >> 2;
        float w2r[3][8], hr[4][8];
        #pragma unroll
        for (int i = 0; i < 3; ++i) {
            int p = 3 * pg + i, pk = p & 7;
            *reinterpret_cast<float4*>(&w2r[i][0]) =
                *reinterpret_cast<const float4*>(&w2t[p * 256 + (((gk0 + 0) ^ pk) << 2)]);
            *reinterpret_cast<float4*>(&w2r[i][4]) =
                *reinterpret_cast<const float4*>(&w2t[p * 256 + (((gk0 + 1) ^ pk) << 2)]);
        }
        #pragma unroll
        for (int j = 0; j < 4; ++j) {
            int bb = 4 * bq + j;
            *reinterpret_cast<float4*>(&hr[j][0]) =
                *reinterpret_cast<const float4*>(&h_s[bb * 256 + (((gk0 + 0) ^ bq) << 2)]);
            *reinterpret_cast<float4*>(&hr[j][4]) =
                *reinterpret_cast<const float4*>(&h_s[bb * 256 + (((gk0 + 1) ^ bq) << 2)]);
        }
        #pragma unroll
        for (int kk = 0; kk < 8; ++kk)
            #pragma unroll
            for (int j = 0; j < 4; ++j)
                #pragma unroll
                for (int i = 0; i < 3; ++i)
                    acc2[j][i] = fmaf(hr[j][kk], w2r[i][kk], acc2[j][i]);
    }
    __syncthreads();
    #pragma unroll
    for (int j = 0; j < 4; ++j)
        #pragma unroll
        for (int i = 0; i < 3; ++i)
            part[((wv_ << 5) + 4 * bq + j) * PK_TOT + 3 * pg + i] = acc2[j][i];
    __syncthreads();

    {
        const int eb = tid >> 3;
        const int ej = tid & 7;
        float rawa = b2[(size_t)r * PK_TOT + ej];
        float rawb = b2[(size_t)r * PK_TOT + 8 + ej];
        float rawr = b2[(size_t)r * PK_TOT + 16 + ej];
        #pragma unroll
        for (int w = 0; w < 4; ++w) {
            rawa += part[((w << 5) + eb) * PK_TOT + ej];
            rawb += part[((w << 5) + eb) * PK_TOT + 8 + ej];
            rawr += part[((w << 5) + eb) * PK_TOT + 16 + ej];
        }
        float zi = z_t[(r + 1) * 32 + eb];
        float t  = tanf((zi - PI_F) * 0.5f);
        float al = expf(rawa);
        float g  = fmaf(al, t, rawb);
        float X  = 2.0f * atanf(g) + PI_F;
        float dv = al * (1.0f + t * t) / (1.0f + g * g);
        float m = rawr;
        m = fmaxf(m, __shfl_xor(m, 1));
        m = fmaxf(m, __shfl_xor(m, 2));
        m = fmaxf(m, __shfl_xor(m, 4));
        float e  = expf(rawr - m);
        float se = e, sx = e * X, sd = e * dv;
        se += __shfl_xor(se, 1); se += __shfl_xor(se, 2); se += __shfl_xor(se, 4);
        sx += __shfl_xor(sx, 1); sx += __shfl_xor(sx, 2); sx += __shfl_xor(sx, 4);
        sd += __shfl_xor(sd, 1); sd += __shfl_xor(sd, 2); sd += __shfl_xor(sd, 4);
        if (ej == 0) {
            int gb = b0 + eb;
            out[(size_t)gb * D_TOT + (r + 1)] = sx / se;
            atomicAdd(&out[(size_t)B_TOT * D_TOT + gb], logf(sd / se));
        }
    }
}

extern "C" void kernel_launch(void* const* d_in, const int* in_sizes, int n_in,
                              void* d_out, int out_size, void* d_ws, size_t ws_size,
                              hipStream_t stream) {
    const float* z  = (const float*)d_in[0];
    const float* W1 = (const float*)d_in[1];
    const float* b1 = (const float*)d_in[2];
    const float* W2 = (const float*)d_in[3];
    const float* b2 = (const float*)d_in[4];
    float* out = (float*)d_out;

    init_out_kernel<<<dim3(B_TOT / 256), dim3(256), 0, stream>>>(out);
    if (ws_size >= (size_t)WS_NEED) {
        prep_weights<<<dim3(756), dim3(256), 0, stream>>>(W1, b1, W2, (unsigned int*)d_ws);
        flow_mfma<<<dim3(B_TOT / 64, R_TOT), dim3(256), 0, stream>>>(
            z, (const unsigned int*)d_ws, b2, out);
    } else {
        flow_fp32<<<dim3(B_TOT / 32, R_TOT), dim3(256), 0, stream>>>(z, W1, b1, W2, b2, out);
    }
}

// Round 8
// 116.651 us; speedup vs baseline: 4.2879x; 1.2277x over previous
//
#include <hip/hip_runtime.h>
#include <math.h>
#include <type_traits>

typedef __bf16 bf16x8 __attribute__((ext_vector_type(8)));
typedef float f32x4 __attribute__((ext_vector_type(4)));
typedef unsigned int u32x4 __attribute__((ext_vector_type(4)));

#define B_TOT 16384
#define D_TOT 64
#define R_TOT 63
#define H_TOT 256
#define PK_TOT 24
#define PI_F 3.14159265358979323846f

// ws layout (u32 units): W1F frags [((r*16+nt)*2+t)] then W2F frags [(r*2+nt2)*8+ks]
// all single-plane RTNE bf16.
#define W2F_BASE_U32 516096u
#define WS_NEED 3096576u

#define MFMA16(a, b, c) __builtin_amdgcn_mfma_f32_16x16x32_bf16((a), (b), (c), 0, 0, 0)

__device__ __forceinline__ unsigned short bf16_rtne(float f) {
    unsigned u = __float_as_uint(f);
    unsigned rr = u + 0x7FFFu + ((u >> 16) & 1u);
    return (unsigned short)(rr >> 16);
}

// one v_cvt_pk_bf16_f32: packs rtne(a) | rtne(b)<<16 (no builtin on gfx950)
__device__ __forceinline__ unsigned cvt_pk_bf16(float a, float b) {
    unsigned r;
    asm("v_cvt_pk_bf16_f32 %0, %1, %2" : "=v"(r) : "v"(a), "v"(b));
    return r;
}

__global__ void init_out_kernel(float* __restrict__ out) {
    int b = blockIdx.x * 256 + threadIdx.x;
    if (b < B_TOT) {
        out[(size_t)b * D_TOT] = 0.0f;            // x[:,0] = 0
        out[(size_t)B_TOT * D_TOT + b] = 0.0f;    // log_det = 0
    }
}

// ---------------- prep: weights -> single-plane RTNE bf16 MFMA fragments ----------------
// Bias trick: b1[r] in free padded K-row (d=31 for r<=30, d=63 for r>=31);
// main kernel forces staged z at that row to 1.0.
__global__ void prep_weights(const float* __restrict__ W1,
                             const float* __restrict__ b1,
                             const float* __restrict__ W2,
                             unsigned int* __restrict__ wsf)
{
    int gid = blockIdx.x * 256 + threadIdx.x;
    if (gid >= 193536) return;
    float v[8];
    unsigned int* dst;
    if (gid < 129024) {
        int lane = gid & 63;
        int q = gid >> 6;                  // frag idx 0..2015 = ((r*16+nt)*2+t)
        int t = q & 1; int qq = q >> 1;
        int nt = qq & 15; int r = qq >> 4;
        int n  = (nt << 4) + (lane & 15);
        int kb = (t << 5) + ((lane >> 4) << 3);
        int bias_d = (r <= 30) ? 31 : 63;
        #pragma unroll
        for (int j = 0; j < 8; ++j) {
            int d = kb + j;
            v[j] = (d <= r) ? W1[(size_t)(r * 64 + d) * 256 + n]
                 : (d == bias_d ? b1[(size_t)r * 256 + n] : 0.0f);
        }
        dst = wsf + (size_t)q * 256 + ((unsigned)lane << 2);
    } else {
        int g2 = gid - 129024;
        int lane = g2 & 63;
        int q = g2 >> 6;                   // frag idx 0..1007 = (r*2+nt)*8+ks
        int ks = q & 7; int qq = q >> 3;
        int nt = qq & 1; int r = qq >> 1;
        int n  = (nt << 4) + (lane & 15);
        int kb = (ks << 5) + ((lane >> 4) << 3);
        #pragma unroll
        for (int j = 0; j < 8; ++j) {
            int k = kb + j;
            v[j] = (n < PK_TOT) ? W2[(size_t)(r * 256 + k) * PK_TOT + n] : 0.0f;
        }
        dst = wsf + W2F_BASE_U32 + (size_t)q * 256 + ((unsigned)lane << 2);
    }
    unsigned hw[4];
    #pragma unroll
    for (int i = 0; i < 4; ++i)
        hw[i] = (unsigned)bf16_rtne(v[2 * i]) | ((unsigned)bf16_rtne(v[2 * i + 1]) << 16);
    *reinterpret_cast<u32x4*>(dst) = u32x4{hw[0], hw[1], hw[2], hw[3]};
}

// ---------------- main MFMA kernel: block = 64 batches x one r, 4 waves ----------------
// m-split phasing, all-bf16 single-plane operands (z, W1, h, W2 all RTNE bf16;
// f32 accumulate). LDS 24KB: z [0,8K), h/partials [8K,24K).
// Liveness ~80 regs -> (256,5) cap 102 fits; WRITE_SIZE is the spill canary
// (round 7: 66MB scratch writes at cap 102 with the z lo-plane still present).
__global__ __launch_bounds__(256, 5) void flow_mfma(
    const float* __restrict__ z, const unsigned int* __restrict__ wsf,
    const float* __restrict__ b2, float* __restrict__ out)
{
    const int r   = blockIdx.y;
    const int b0  = blockIdx.x << 6;
    const int tid = threadIdx.x;
    const int w   = tid >> 6;
    const int l   = tid & 63;
    const int l15 = l & 15, l4 = l >> 4, key = l & 7;

    __shared__ __align__(16) unsigned char sm[24576];

    // ---- stage z as single-plane RTNE bf16; bias row -> 1.0 ----
    {
        const int m  = tid >> 2;
        const int dq = (tid & 3) << 4;
        const float* zp = z + (size_t)(b0 + m) * 64 + dq;
        const int mkey = m & 7;
        const int bias_d = (r <= 30) ? 31 : 63;
        const int rel = bias_d - dq;            // in [0,16) only for the owning thread
        #pragma unroll
        for (int qq = 0; qq < 4; ++qq) {
            float4 val = *reinterpret_cast<const float4*>(zp + (qq << 2));
            int d0 = dq + (qq << 2);
            float vv[4] = {val.x, val.y, val.z, val.w};
            if ((rel >> 2) == qq) vv[rel & 3] = 1.0f;   // bias row (exact in bf16)
            uint2 hv;
            hv.x = cvt_pk_bf16(vv[0], vv[1]);
            hv.y = cvt_pk_bf16(vv[2], vv[3]);
            int off = (m << 7) + ((((d0 >> 3)) ^ mkey) << 4) + (((d0 >> 2) & 1) << 3);
            *reinterpret_cast<uint2*>(sm + off) = hv;
        }
    }
    __syncthreads();

    const unsigned int* w1b = wsf + (size_t)((r * 16 + (w << 2)) * 2) * 256 + (l << 2);
    const unsigned int* w2b = wsf + W2F_BASE_U32 + (size_t)(r * 16) * 256 + (l << 2);

    #pragma unroll 1
    for (int mh = 0; mh < 2; ++mh) {
        // ---- GEMM1 for batches mh*32..+32: D1[n][m] = sum_d W1m[d][n]*z[m][d] ----
        f32x4 acc1[4][2];
        #pragma unroll
        for (int a = 0; a < 4; ++a)
            #pragma unroll
            for (int b = 0; b < 2; ++b) acc1[a][b] = f32x4{0.f, 0.f, 0.f, 0.f};

        auto run_gemm1 = [&](auto FULLC) {
            constexpr int NT = decltype(FULLC)::value ? 2 : 1;
            #pragma unroll
            for (int t = 0; t < NT; ++t) {
                bf16x8 zf[2];   // [mt] single plane
                #pragma unroll
                for (int mt = 0; mt < 2; ++mt) {
                    int m = (mh << 5) + (mt << 4) + l15;
                    int off = (m << 7) + ((((t << 2) + l4) ^ key) << 4);
                    zf[mt] = __builtin_bit_cast(bf16x8, *reinterpret_cast<u32x4*>(sm + off));
                }
                #pragma unroll
                for (int ntl = 0; ntl < 4; ++ntl) {
                    bf16x8 af = __builtin_bit_cast(bf16x8,
                        *reinterpret_cast<const u32x4*>(w1b + (((ntl << 1) + t) << 8)));
                    #pragma unroll
                    for (int mt = 0; mt < 2; ++mt)
                        acc1[ntl][mt] = MFMA16(af, zf[mt], acc1[ntl][mt]);
                }
            }
        };
        if (r >= 31) run_gemm1(std::true_type{});
        else         run_gemm1(std::false_type{});

        // ---- relu + RTNE bf16, write h tile [32][256]bf16 at 8192 (row 512B) ----
        #pragma unroll
        for (int ntl = 0; ntl < 4; ++ntl) {
            #pragma unroll
            for (int mt = 0; mt < 2; ++mt) {
                float v0 = fmaxf(acc1[ntl][mt][0], 0.0f);
                float v1 = fmaxf(acc1[ntl][mt][1], 0.0f);
                float v2 = fmaxf(acc1[ntl][mt][2], 0.0f);
                float v3 = fmaxf(acc1[ntl][mt][3], 0.0f);
                uint2 hv;
                hv.x = cvt_pk_bf16(v0, v1);
                hv.y = cvt_pk_bf16(v2, v3);
                int mloc = (mt << 4) + l15;
                int g    = (w << 3) + (ntl << 1) + (l4 >> 1);           // granule 0..31
                int off  = 8192 + (mloc << 9)
                         + (((g & 24) | ((g ^ key) & 7)) << 4) + ((l4 & 1) << 3);
                *reinterpret_cast<uint2*>(sm + off) = hv;
            }
        }
        __syncthreads();

        // ---- gemm2 full-K, k-split: wave w covers k = w*64..w*64+63 ----
        f32x4 acc2[2][2];
        #pragma unroll
        for (int a = 0; a < 2; ++a)
            #pragma unroll
            for (int b = 0; b < 2; ++b) acc2[a][b] = f32x4{0.f, 0.f, 0.f, 0.f};

        #pragma unroll
        for (int kk = 0; kk < 2; ++kk) {
            const int ks = (w << 1) + kk;
            bf16x8 wf[2];
            #pragma unroll
            for (int nt2 = 0; nt2 < 2; ++nt2)
                wf[nt2] = __builtin_bit_cast(bf16x8,
                    *reinterpret_cast<const u32x4*>(w2b + (((nt2 << 3) + ks) << 8)));
            bf16x8 hfr[2];
            #pragma unroll
            for (int mt = 0; mt < 2; ++mt) {
                int mloc = (mt << 4) + l15;
                int g    = (ks << 2) + l4;
                int off  = 8192 + (mloc << 9)
                         + (((g & 24) | ((g ^ key) & 7)) << 4);
                hfr[mt] = __builtin_bit_cast(bf16x8, *reinterpret_cast<u32x4*>(sm + off));
            }
            #pragma unroll
            for (int nt2 = 0; nt2 < 2; ++nt2)
                #pragma unroll
                for (int mt = 0; mt < 2; ++mt)
                    acc2[nt2][mt] = MFMA16(wf[nt2], hfr[mt], acc2[nt2][mt]);
        }
        __syncthreads();   // h reads done; alias region as partials

        // ---- partials [4 waves][32 m][32 p-pad] f32 = 16KB over h region ----
        #pragma unroll
        for (int nt2 = 0; nt2 < 2; ++nt2)
            #pragma unroll
            for (int mt = 0; mt < 2; ++mt) {
                int row = (w << 5) + (mt << 4) + l15;
                int off = 8192 + (row << 7) + ((((nt2 << 2) + l4) ^ key) << 4);
                *reinterpret_cast<f32x4*>(sm + off) = acc2[nt2][mt];
            }
        __syncthreads();

        // ---- flow epilogue for this batch-half: thread = (mloc = tid>>3, j = tid&7) ----
        {
            const int mloc = tid >> 3;
            const int j    = tid & 7;
            const int mk   = mloc & 7;
            float ra = b2[(size_t)r * 24 + j];
            float rb = b2[(size_t)r * 24 + 8 + j];
            float rr = b2[(size_t)r * 24 + 16 + j];
            #pragma unroll
            for (int w4 = 0; w4 < 4; ++w4) {
                const int base = 8192 + (((w4 << 5) + mloc) << 7);
                const int sub  = (j & 3) << 2;
                ra += *reinterpret_cast<float*>(sm + base + ((((j) >> 2) ^ mk) << 4) + sub);
                rb += *reinterpret_cast<float*>(sm + base + (((2 + (j >> 2)) ^ mk) << 4) + sub);
                rr += *reinterpret_cast<float*>(sm + base + (((4 + (j >> 2)) ^ mk) << 4) + sub);
            }
            int gb = b0 + (mh << 5) + mloc;
            float zi = z[(size_t)gb * 64 + r + 1];
            // tan((zi-pi)/2) == -cos(zi/2)/sin(zi/2); clamp avoids inf^2/inf^2 NaN at zi=0
            float s, c;
            __sincosf(zi * 0.5f, &s, &c);
            float t = -c * __builtin_amdgcn_rcpf(s);
            t = fminf(fmaxf(t, -1e8f), 1e8f);
            float al = __expf(ra);
            float g  = fmaf(al, t, rb);
            float X  = 2.0f * atanf(g) + PI_F;
            float dv = al * fmaf(t, t, 1.0f) * __builtin_amdgcn_rcpf(fmaf(g, g, 1.0f));
            float mx = rr;
            mx = fmaxf(mx, __shfl_xor(mx, 1));
            mx = fmaxf(mx, __shfl_xor(mx, 2));
            mx = fmaxf(mx, __shfl_xor(mx, 4));
            float e = __expf(rr - mx);
            float se = e, sx = e * X, sd = e * dv;
            se += __shfl_xor(se, 1); se += __shfl_xor(se, 2); se += __shfl_xor(se, 4);
            sx += __shfl_xor(sx, 1); sx += __shfl_xor(sx, 2); sx += __shfl_xor(sx, 4);
            sd += __shfl_xor(sd, 1); sd += __shfl_xor(sd, 2); sd += __shfl_xor(sd, 4);
            if (j == 0) {
                float rse = __builtin_amdgcn_rcpf(se);
                out[(size_t)gb * D_TOT + r + 1] = sx * rse;
                atomicAdd(&out[(size_t)B_TOT * D_TOT + gb], __logf(sd * rse));
            }
        }
        __syncthreads();   // partial region reused as h tile next half
    }
}

// ---------------- fp32 fallback (round-1 kernel, known-correct) ----------------
__global__ __launch_bounds__(256, 2) void flow_fp32(
    const float* __restrict__ z,  const float* __restrict__ W1,
    const float* __restrict__ b1, const float* __restrict__ W2,
    const float* __restrict__ b2, float* __restrict__ out)
{
    const int r   = blockIdx.y;
    const int b0  = blockIdx.x * 32;
    const int tid = threadIdx.x;

    __shared__ float smem[16384];
    float* z_t  = smem;
    float* h_s  = smem + 2048;
    float* w2t  = smem + 2048 + 8192;
    float* part = w2t;

    #pragma unroll
    for (int it = 0; it < 2; ++it) {
        int idx4 = it * 256 + tid;
        int brow = idx4 >> 4;
        int dq   = (idx4 & 15) << 2;
        float4 v = *reinterpret_cast<const float4*>(&z[(size_t)(b0 + brow) * D_TOT + dq]);
        z_t[(dq + 0) * 32 + brow] = v.x;
        z_t[(dq + 1) * 32 + brow] = v.y;
        z_t[(dq + 2) * 32 + brow] = v.z;
        z_t[(dq + 3) * 32 + brow] = v.w;
    }
    #pragma unroll
    for (int it = 0; it < 6; ++it) {
        int idx4 = it * 256 + tid;
        int k  = idx4 / 6;
        int pq = (idx4 - k * 6) << 2;
        float4 v = *reinterpret_cast<const float4*>(&W2[(size_t)(r * H_TOT + k) * PK_TOT + pq]);
        int gk = k >> 2, kq = k & 3;
        w2t[(pq + 0) * 256 + (((gk) ^ ((pq + 0) & 7)) << 2) + kq] = v.x;
        w2t[(pq + 1) * 256 + (((gk) ^ ((pq + 1) & 7)) << 2) + kq] = v.y;
        w2t[(pq + 2) * 256 + (((gk) ^ ((pq + 2) & 7)) << 2) + kq] = v.z;
        w2t[(pq + 3) * 256 + (((gk) ^ ((pq + 3) & 7)) << 2) + kq] = v.w;
    }
    __syncthreads();

    const int rg = tid & 15;
    const int cg = tid >> 4;
    float acc[2][16];
    #pragma unroll
    for (int j = 0; j < 2; ++j)
        #pragma unroll
        for (int i = 0; i < 16; ++i) acc[j][i] = 0.0f;

    const float* w1p = W1 + (size_t)(r * D_TOT) * H_TOT + (cg << 4);
    #pragma unroll 4
    for (int d = 0; d <= r; ++d) {
        float2 zv = *reinterpret_cast<const float2*>(&z_t[d * 32 + (rg << 1)]);
        const float* wrow = w1p + (size_t)d * H_TOT;
        float wv[16];
        *reinterpret_cast<float4*>(&wv[0])  = *reinterpret_cast<const float4*>(wrow + 0);
        *reinterpret_cast<float4*>(&wv[4])  = *reinterpret_cast<const float4*>(wrow + 4);
        *reinterpret_cast<float4*>(&wv[8])  = *reinterpret_cast<const float4*>(wrow + 8);
        *reinterpret_cast<float4*>(&wv[12]) = *reinterpret_cast<const float4*>(wrow + 12);
        #pragma unroll
        for (int i = 0; i < 16; ++i) {
            acc[0][i] = fmaf(zv.x, wv[i], acc[0][i]);
            acc[1][i] = fmaf(zv.y, wv[i], acc[1][i]);
        }
    }
    {
        const int key = (rg >> 1) & 7;
        #pragma unroll
        for (int gi = 0; gi < 4; ++gi) {
            float4 bv = *reinterpret_cast<const float4*>(&b1[(size_t)r * H_TOT + (cg << 4) + (gi << 2)]);
            #pragma unroll
            for (int j = 0; j < 2; ++j) {
                float4 v;
                v.x = fmaxf(acc[j][4 * gi + 0] + bv.x, 0.0f);
                v.y = fmaxf(acc[j][4 * gi + 1] + bv.y, 0.0f);
                v.z = fmaxf(acc[j][4 * gi + 2] + bv.z, 0.0f);
                v.w = fmaxf(acc[j][4 * gi + 3] + bv.w, 0.0f);
                int bb = (rg << 1) + j;
                int g  = ((cg << 2) + gi) ^ key;
                *reinterpret_cast<float4*>(&h_s[bb * 256 + (g << 2)]) = v;
            }
        }
    }
    __syncthreads();

    const int wv_ = tid >> 6;
    const int ln  = tid & 63;
    const int bq  = ln & 7;
    const int pg  = ln >> 3;
    float acc2[4][3];
    #pragma unroll
    for (int j = 0; j < 4; ++j)
        #pragma unroll
        for (int i = 0; i < 3; ++i) acc2[j][i] = 0.0f;

    #pragma unroll
    for (int c = 0; c < 8; ++c) {
        int k0  = (wv_ << 6) + (c << 3);
        int gk0 = k0 >> 2;
        float w2r[3][8], hr[4][8];
        #pragma unroll
        for (int i = 0; i < 3; ++i) {
            int p = 3 * pg + i, pk = p & 7;
            *reinterpret_cast<float4*>(&w2r[i][0]) =
                *reinterpret_cast<const float4*>(&w2t[p * 256 + (((gk0 + 0) ^ pk) << 2)]);
            *reinterpret_cast<float4*>(&w2r[i][4]) =
                *reinterpret_cast<const float4*>(&w2t[p * 256 + (((gk0 + 1) ^ pk) << 2)]);
        }
        #pragma unroll
        for (int j = 0; j < 4; ++j) {
            int bb = 4 * bq + j;
            *reinterpret_cast<float4*>(&hr[j][0]) =
                *reinterpret_cast<const float4*>(&h_s[bb * 256 + (((gk0 + 0) ^ bq) << 2)]);
            *reinterpret_cast<float4*>(&hr[j][4]) =
                *reinterpret_cast<const float4*>(&h_s[bb * 256 + (((gk0 + 1) ^ bq) << 2)]);
        }
        #pragma unroll
        for (int kk = 0; kk < 8; ++kk)
            #pragma unroll
            for (int j = 0; j < 4; ++j)
                #pragma unroll
                for (int i = 0; i < 3; ++i)
                    acc2[j][i] = fmaf(hr[j][kk], w2r[i][kk], acc2[j][i]);
    }
    __syncthreads();
    #pragma unroll
    for (int j = 0; j < 4; ++j)
        #pragma unroll
        for (int i = 0; i < 3; ++i)
            part[((wv_ << 5) + 4 * bq + j) * PK_TOT + 3 * pg + i] = acc2[j][i];
    __syncthreads();

    {
        const int eb = tid >> 3;
        const int ej = tid & 7;
        float rawa = b2[(size_t)r * PK_TOT + ej];
        float rawb = b2[(size_t)r * PK_TOT + 8 + ej];
        float rawr = b2[(size_t)r * PK_TOT + 16 + ej];
        #pragma unroll
        for (int w = 0; w < 4; ++w) {
            rawa += part[((w << 5) + eb) * PK_TOT + ej];
            rawb += part[((w << 5) + eb) * PK_TOT + 8 + ej];
            rawr += part[((w << 5) + eb) * PK_TOT + 16 + ej];
        }
        float zi = z_t[(r + 1) * 32 + eb];
        float t  = tanf((zi - PI_F) * 0.5f);
        float al = expf(rawa);
        float g  = fmaf(al, t, rawb);
        float X  = 2.0f * atanf(g) + PI_F;
        float dv = al * (1.0f + t * t) / (1.0f + g * g);
        float m = rawr;
        m = fmaxf(m, __shfl_xor(m, 1));
        m = fmaxf(m, __shfl_xor(m, 2));
        m = fmaxf(m, __shfl_xor(m, 4));
        float e  = expf(rawr - m);
        float se = e, sx = e * X, sd = e * dv;
        se += __shfl_xor(se, 1); se += __shfl_xor(se, 2); se += __shfl_xor(se, 4);
        sx += __shfl_xor(sx, 1); sx += __shfl_xor(sx, 2); sx += __shfl_xor(sx, 4);
        sd += __shfl_xor(sd, 1); sd += __shfl_xor(sd, 2); sd += __shfl_xor(sd, 4);
        if (ej == 0) {
            int gb = b0 + eb;
            out[(size_t)gb * D_TOT + (r + 1)] = sx / se;
            atomicAdd(&out[(size_t)B_TOT * D_TOT + gb], logf(sd / se));
        }
    }
}

extern "C" void kernel_launch(void* const* d_in, const int* in_sizes, int n_in,
                              void* d_out, int out_size, void* d_ws, size_t ws_size,
                              hipStream_t stream) {
    const float* z  = (const float*)d_in[0];
    const float* W1 = (const float*)d_in[1];
    const float* b1 = (const float*)d_in[2];
    const float* W2 = (const float*)d_in[3];
    const float* b2 = (const float*)d_in[4];
    float* out = (float*)d_out;

    init_out_kernel<<<dim3(B_TOT / 256), dim3(256), 0, stream>>>(out);
    if (ws_size >= (size_t)WS_NEED) {
        prep_weights<<<dim3(756), dim3(256), 0, stream>>>(W1, b1, W2, (unsigned int*)d_ws);
        flow_mfma<<<dim3(B_TOT / 64, R_TOT), dim3(256), 0, stream>>>(
            z, (const unsigned int*)d_ws, b2, out);
    } else {
        flow_fp32<<<dim3(B_TOT / 32, R_TOT), dim3(256), 0, stream>>>(z, W1, b1, W2, b2, out);
    }
}

// Round 9
// 110.995 us; speedup vs baseline: 4.5065x; 1.0510x over previous
//
#include <hip/hip_runtime.h>
#include <math.h>
#include <type_traits>

typedef __bf16 bf16x8 __attribute__((ext_vector_type(8)));
typedef float f32x4 __attribute__((ext_vector_type(4)));
typedef unsigned int u32x4 __attribute__((ext_vector_type(4)));

#define B_TOT 16384
#define D_TOT 64
#define R_TOT 63
#define H_TOT 256
#define PK_TOT 24
#define PI_F 3.14159265358979323846f

// ws layout (u32 units): W1F frags [((r*16+nt)*2+t)] then W2F frags [(r*2+nt2)*8+ks]
// all single-plane RTNE bf16.
#define W2F_BASE_U32 516096u
#define WS_NEED 3096576u

#define MFMA16(a, b, c) __builtin_amdgcn_mfma_f32_16x16x32_bf16((a), (b), (c), 0, 0, 0)

__device__ __forceinline__ unsigned short bf16_rtne(float f) {
    unsigned u = __float_as_uint(f);
    unsigned rr = u + 0x7FFFu + ((u >> 16) & 1u);
    return (unsigned short)(rr >> 16);
}

// one v_cvt_pk_bf16_f32: packs rtne(a) | rtne(b)<<16 (no builtin on gfx950)
__device__ __forceinline__ unsigned cvt_pk_bf16(float a, float b) {
    unsigned r;
    asm("v_cvt_pk_bf16_f32 %0, %1, %2" : "=v"(r) : "v"(a), "v"(b));
    return r;
}

__global__ void init_out_kernel(float* __restrict__ out) {
    int b = blockIdx.x * 256 + threadIdx.x;
    if (b < B_TOT) {
        out[(size_t)b * D_TOT] = 0.0f;            // x[:,0] = 0
        out[(size_t)B_TOT * D_TOT + b] = 0.0f;    // log_det = 0
    }
}

// ---------------- prep: weights -> single-plane RTNE bf16 MFMA fragments ----------------
// Bias trick: b1[r] in free padded K-row (d=31 for r<=30, d=63 for r>=31);
// main kernel forces staged z at that row to 1.0.
__global__ void prep_weights(const float* __restrict__ W1,
                             const float* __restrict__ b1,
                             const float* __restrict__ W2,
                             unsigned int* __restrict__ wsf)
{
    int gid = blockIdx.x * 256 + threadIdx.x;
    if (gid >= 193536) return;
    float v[8];
    unsigned int* dst;
    if (gid < 129024) {
        int lane = gid & 63;
        int q = gid >> 6;                  // frag idx 0..2015 = ((r*16+nt)*2+t)
        int t = q & 1; int qq = q >> 1;
        int nt = qq & 15; int r = qq >> 4;
        int n  = (nt << 4) + (lane & 15);
        int kb = (t << 5) + ((lane >> 4) << 3);
        int bias_d = (r <= 30) ? 31 : 63;
        #pragma unroll
        for (int j = 0; j < 8; ++j) {
            int d = kb + j;
            v[j] = (d <= r) ? W1[(size_t)(r * 64 + d) * 256 + n]
                 : (d == bias_d ? b1[(size_t)r * 256 + n] : 0.0f);
        }
        dst = wsf + (size_t)q * 256 + ((unsigned)lane << 2);
    } else {
        int g2 = gid - 129024;
        int lane = g2 & 63;
        int q = g2 >> 6;                   // frag idx 0..1007 = (r*2+nt)*8+ks
        int ks = q & 7; int qq = q >> 3;
        int nt = qq & 1; int r = qq >> 1;
        int n  = (nt << 4) + (lane & 15);
        int kb = (ks << 5) + ((lane >> 4) << 3);
        #pragma unroll
        for (int j = 0; j < 8; ++j) {
            int k = kb + j;
            v[j] = (n < PK_TOT) ? W2[(size_t)(r * 256 + k) * PK_TOT + n] : 0.0f;
        }
        dst = wsf + W2F_BASE_U32 + (size_t)q * 256 + ((unsigned)lane << 2);
    }
    unsigned hw[4];
    #pragma unroll
    for (int i = 0; i < 4; ++i)
        hw[i] = (unsigned)bf16_rtne(v[2 * i]) | ((unsigned)bf16_rtne(v[2 * i + 1]) << 16);
    *reinterpret_cast<u32x4*>(dst) = u32x4{hw[0], hw[1], hw[2], hw[3]};
}

// ---------------- main MFMA kernel: block = 64 batches x one r, 4 waves ----------------
// m-split phasing, all-bf16 single-plane operands (f32 accumulate).
// LDS: z [0,8K), h/partials [8K,24K), t-cache [24K, 24K+256B).
// (256,4): reg cap 128 >= ~107 liveness (the (256,5) cap ~102 spilled: round 7/8
// WRITE_SIZE 66-76MB scratch). 4 blocks x 4 waves = 16 waves/CU = same occupancy
// as the spilling (256,5) build, minus the scratch traffic.
__global__ __launch_bounds__(256, 4) void flow_mfma(
    const float* __restrict__ z, const unsigned int* __restrict__ wsf,
    const float* __restrict__ b2, float* __restrict__ out)
{
    const int r   = blockIdx.y;
    const int b0  = blockIdx.x << 6;
    const int tid = threadIdx.x;
    const int w   = tid >> 6;
    const int l   = tid & 63;
    const int l15 = l & 15, l4 = l >> 4, key = l & 7;

    __shared__ __align__(16) unsigned char sm[24832];
    float* tls = reinterpret_cast<float*>(sm + 24576);   // t per batch (64 f32)

    // ---- stage z as single-plane RTNE bf16; bias row -> 1.0; t computed once/batch ----
    {
        const int m  = tid >> 2;
        const int dq = (tid & 3) << 4;
        const float* zp = z + (size_t)(b0 + m) * 64 + dq;
        const int mkey = m & 7;
        const int bias_d = (r <= 30) ? 31 : 63;
        const int rel = bias_d - dq;            // in [0,16) only for the owning thread
        const int tel = (r + 1) - dq;           // in [0,16) only for the t-owner thread
        #pragma unroll
        for (int qq = 0; qq < 4; ++qq) {
            float4 val = *reinterpret_cast<const float4*>(zp + (qq << 2));
            int d0 = dq + (qq << 2);
            float vv[4] = {val.x, val.y, val.z, val.w};
            // t = tan((zi-pi)/2) = -cos(zi/2)/sin(zi/2), from pre-rounding f32;
            // MUST precede the bias overwrite (r=30/62: bias_d == r+1).
            if ((tel >> 2) == qq) {
                float zi = vv[tel & 3];
                float s, c;
                __sincosf(zi * 0.5f, &s, &c);
                float t = -c * __builtin_amdgcn_rcpf(s);
                tls[m] = fminf(fmaxf(t, -1e8f), 1e8f);
            }
            if ((rel >> 2) == qq) vv[rel & 3] = 1.0f;   // bias row (exact in bf16)
            uint2 hv;
            hv.x = cvt_pk_bf16(vv[0], vv[1]);
            hv.y = cvt_pk_bf16(vv[2], vv[3]);
            int off = (m << 7) + ((((d0 >> 3)) ^ mkey) << 4) + (((d0 >> 2) & 1) << 3);
            *reinterpret_cast<uint2*>(sm + off) = hv;
        }
    }
    __syncthreads();

    const unsigned int* w1b = wsf + (size_t)((r * 16 + (w << 2)) * 2) * 256 + (l << 2);
    const unsigned int* w2b = wsf + W2F_BASE_U32 + (size_t)(r * 16) * 256 + (l << 2);

    // hoisted epilogue constants (r-dependent only)
    const int ej  = tid & 7;
    const float b2a = b2[(size_t)r * 24 + ej];
    const float b2b = b2[(size_t)r * 24 + 8 + ej];
    const float b2r = b2[(size_t)r * 24 + 16 + ej];

    #pragma unroll 1
    for (int mh = 0; mh < 2; ++mh) {
        // ---- GEMM1 for batches mh*32..+32: D1[n][m] = sum_d W1m[d][n]*z[m][d] ----
        f32x4 acc1[4][2];
        #pragma unroll
        for (int a = 0; a < 4; ++a)
            #pragma unroll
            for (int b = 0; b < 2; ++b) acc1[a][b] = f32x4{0.f, 0.f, 0.f, 0.f};

        auto run_gemm1 = [&](auto FULLC) {
            constexpr int NT = decltype(FULLC)::value ? 2 : 1;
            #pragma unroll
            for (int t = 0; t < NT; ++t) {
                bf16x8 zf[2];   // [mt] single plane
                #pragma unroll
                for (int mt = 0; mt < 2; ++mt) {
                    int m = (mh << 5) + (mt << 4) + l15;
                    int off = (m << 7) + ((((t << 2) + l4) ^ key) << 4);
                    zf[mt] = __builtin_bit_cast(bf16x8, *reinterpret_cast<u32x4*>(sm + off));
                }
                #pragma unroll
                for (int ntl = 0; ntl < 4; ++ntl) {
                    bf16x8 af = __builtin_bit_cast(bf16x8,
                        *reinterpret_cast<const u32x4*>(w1b + (((ntl << 1) + t) << 8)));
                    #pragma unroll
                    for (int mt = 0; mt < 2; ++mt)
                        acc1[ntl][mt] = MFMA16(af, zf[mt], acc1[ntl][mt]);
                }
            }
        };
        if (r >= 31) run_gemm1(std::true_type{});
        else         run_gemm1(std::false_type{});

        // ---- relu + RTNE bf16, write h tile [32][256]bf16 at 8192 (row 512B) ----
        #pragma unroll
        for (int ntl = 0; ntl < 4; ++ntl) {
            #pragma unroll
            for (int mt = 0; mt < 2; ++mt) {
                float v0 = fmaxf(acc1[ntl][mt][0], 0.0f);
                float v1 = fmaxf(acc1[ntl][mt][1], 0.0f);
                float v2 = fmaxf(acc1[ntl][mt][2], 0.0f);
                float v3 = fmaxf(acc1[ntl][mt][3], 0.0f);
                uint2 hv;
                hv.x = cvt_pk_bf16(v0, v1);
                hv.y = cvt_pk_bf16(v2, v3);
                int mloc = (mt << 4) + l15;
                int g    = (w << 3) + (ntl << 1) + (l4 >> 1);           // granule 0..31
                int off  = 8192 + (mloc << 9)
                         + (((g & 24) | ((g ^ key) & 7)) << 4) + ((l4 & 1) << 3);
                *reinterpret_cast<uint2*>(sm + off) = hv;
            }
        }
        __syncthreads();

        // ---- gemm2 full-K, k-split: wave w covers k = w*64..w*64+63 ----
        f32x4 acc2[2][2];
        #pragma unroll
        for (int a = 0; a < 2; ++a)
            #pragma unroll
            for (int b = 0; b < 2; ++b) acc2[a][b] = f32x4{0.f, 0.f, 0.f, 0.f};

        #pragma unroll
        for (int kk = 0; kk < 2; ++kk) {
            const int ks = (w << 1) + kk;
            bf16x8 wf[2];
            #pragma unroll
            for (int nt2 = 0; nt2 < 2; ++nt2)
                wf[nt2] = __builtin_bit_cast(bf16x8,
                    *reinterpret_cast<const u32x4*>(w2b + (((nt2 << 3) + ks) << 8)));
            bf16x8 hfr[2];
            #pragma unroll
            for (int mt = 0; mt < 2; ++mt) {
                int mloc = (mt << 4) + l15;
                int g    = (ks << 2) + l4;
                int off  = 8192 + (mloc << 9)
                         + (((g & 24) | ((g ^ key) & 7)) << 4);
                hfr[mt] = __builtin_bit_cast(bf16x8, *reinterpret_cast<u32x4*>(sm + off));
            }
            #pragma unroll
            for (int nt2 = 0; nt2 < 2; ++nt2)
                #pragma unroll
                for (int mt = 0; mt < 2; ++mt)
                    acc2[nt2][mt] = MFMA16(wf[nt2], hfr[mt], acc2[nt2][mt]);
        }
        __syncthreads();   // h reads done; alias region as partials

        // ---- partials [4 waves][32 m][32 p-pad] f32 = 16KB over h region ----
        #pragma unroll
        for (int nt2 = 0; nt2 < 2; ++nt2)
            #pragma unroll
            for (int mt = 0; mt < 2; ++mt) {
                int row = (w << 5) + (mt << 4) + l15;
                int off = 8192 + (row << 7) + ((((nt2 << 2) + l4) ^ key) << 4);
                *reinterpret_cast<f32x4*>(sm + off) = acc2[nt2][mt];
            }
        __syncthreads();

        // ---- flow epilogue for this batch-half: thread = (mloc = tid>>3, j = tid&7) ----
        {
            const int mloc = tid >> 3;
            const int j    = ej;
            const int mk   = mloc & 7;
            float ra = b2a, rb = b2b, rr = b2r;
            #pragma unroll
            for (int w4 = 0; w4 < 4; ++w4) {
                const int base = 8192 + (((w4 << 5) + mloc) << 7);
                const int sub  = (j & 3) << 2;
                ra += *reinterpret_cast<float*>(sm + base + ((((j) >> 2) ^ mk) << 4) + sub);
                rb += *reinterpret_cast<float*>(sm + base + (((2 + (j >> 2)) ^ mk) << 4) + sub);
                rr += *reinterpret_cast<float*>(sm + base + (((4 + (j >> 2)) ^ mk) << 4) + sub);
            }
            int gb = b0 + (mh << 5) + mloc;
            float t  = tls[(mh << 5) + mloc];
            float al = __expf(ra);
            float g  = fmaf(al, t, rb);
            float X  = 2.0f * atanf(g) + PI_F;
            float dv = al * fmaf(t, t, 1.0f) * __builtin_amdgcn_rcpf(fmaf(g, g, 1.0f));
            float mx = rr;
            mx = fmaxf(mx, __shfl_xor(mx, 1));
            mx = fmaxf(mx, __shfl_xor(mx, 2));
            mx = fmaxf(mx, __shfl_xor(mx, 4));
            float e = __expf(rr - mx);
            float se = e, sx = e * X, sd = e * dv;
            se += __shfl_xor(se, 1); se += __shfl_xor(se, 2); se += __shfl_xor(se, 4);
            sx += __shfl_xor(sx, 1); sx += __shfl_xor(sx, 2); sx += __shfl_xor(sx, 4);
            sd += __shfl_xor(sd, 1); sd += __shfl_xor(sd, 2); sd += __shfl_xor(sd, 4);
            if (j == 0) {
                float rse = __builtin_amdgcn_rcpf(se);
                out[(size_t)gb * D_TOT + r + 1] = sx * rse;
                atomicAdd(&out[(size_t)B_TOT * D_TOT + gb], __logf(sd * rse));
            }
        }
        __syncthreads();   // partial region reused as h tile next half
    }
}

// ---------------- fp32 fallback (round-1 kernel, known-correct) ----------------
__global__ __launch_bounds__(256, 2) void flow_fp32(
    const float* __restrict__ z,  const float* __restrict__ W1,
    const float* __restrict__ b1, const float* __restrict__ W2,
    const float* __restrict__ b2, float* __restrict__ out)
{
    const int r   = blockIdx.y;
    const int b0  = blockIdx.x * 32;
    const int tid = threadIdx.x;

    __shared__ float smem[16384];
    float* z_t  = smem;
    float* h_s  = smem + 2048;
    float* w2t  = smem + 2048 + 8192;
    float* part = w2t;

    #pragma unroll
    for (int it = 0; it < 2; ++it) {
        int idx4 = it * 256 + tid;
        int brow = idx4 >> 4;
        int dq   = (idx4 & 15) << 2;
        float4 v = *reinterpret_cast<const float4*>(&z[(size_t)(b0 + brow) * D_TOT + dq]);
        z_t[(dq + 0) * 32 + brow] = v.x;
        z_t[(dq + 1) * 32 + brow] = v.y;
        z_t[(dq + 2) * 32 + brow] = v.z;
        z_t[(dq + 3) * 32 + brow] = v.w;
    }
    #pragma unroll
    for (int it = 0; it < 6; ++it) {
        int idx4 = it * 256 + tid;
        int k  = idx4 / 6;
        int pq = (idx4 - k * 6) << 2;
        float4 v = *reinterpret_cast<const float4*>(&W2[(size_t)(r * H_TOT + k) * PK_TOT + pq]);
        int gk = k >> 2, kq = k & 3;
        w2t[(pq + 0) * 256 + (((gk) ^ ((pq + 0) & 7)) << 2) + kq] = v.x;
        w2t[(pq + 1) * 256 + (((gk) ^ ((pq + 1) & 7)) << 2) + kq] = v.y;
        w2t[(pq + 2) * 256 + (((gk) ^ ((pq + 2) & 7)) << 2) + kq] = v.z;
        w2t[(pq + 3) * 256 + (((gk) ^ ((pq + 3) & 7)) << 2) + kq] = v.w;
    }
    __syncthreads();

    const int rg = tid & 15;
    const int cg = tid >> 4;
    float acc[2][16];
    #pragma unroll
    for (int j = 0; j < 2; ++j)
        #pragma unroll
        for (int i = 0; i < 16; ++i) acc[j][i] = 0.0f;

    const float* w1p = W1 + (size_t)(r * D_TOT) * H_TOT + (cg << 4);
    #pragma unroll 4
    for (int d = 0; d <= r; ++d) {
        float2 zv = *reinterpret_cast<const float2*>(&z_t[d * 32 + (rg << 1)]);
        const float* wrow = w1p + (size_t)d * H_TOT;
        float wv[16];
        *reinterpret_cast<float4*>(&wv[0])  = *reinterpret_cast<const float4*>(wrow + 0);
        *reinterpret_cast<float4*>(&wv[4])  = *reinterpret_cast<const float4*>(wrow + 4);
        *reinterpret_cast<float4*>(&wv[8])  = *reinterpret_cast<const float4*>(wrow + 8);
        *reinterpret_cast<float4*>(&wv[12]) = *reinterpret_cast<const float4*>(wrow + 12);
        #pragma unroll
        for (int i = 0; i < 16; ++i) {
            acc[0][i] = fmaf(zv.x, wv[i], acc[0][i]);
            acc[1][i] = fmaf(zv.y, wv[i], acc[1][i]);
        }
    }
    {
        const int key = (rg >> 1) & 7;
        #pragma unroll
        for (int gi = 0; gi < 4; ++gi) {
            float4 bv = *reinterpret_cast<const float4*>(&b1[(size_t)r * H_TOT + (cg << 4) + (gi << 2)]);
            #pragma unroll
            for (int j = 0; j < 2; ++j) {
                float4 v;
                v.x = fmaxf(acc[j][4 * gi + 0] + bv.x, 0.0f);
                v.y = fmaxf(acc[j][4 * gi + 1] + bv.y, 0.0f);
                v.z = fmaxf(acc[j][4 * gi + 2] + bv.z, 0.0f);
                v.w = fmaxf(acc[j][4 * gi + 3] + bv.w, 0.0f);
                int bb = (rg << 1) + j;
                int g  = ((cg << 2) + gi) ^ key;
                *reinterpret_cast<float4*>(&h_s[bb * 256 + (g << 2)]) = v;
            }
        }
    }
    __syncthreads();

    const int wv_ = tid >> 6;
    const int ln  = tid & 63;
    const int bq  = ln & 7;
    const int pg  = ln >> 3;
    float acc2[4][3];
    #pragma unroll
    for (int j = 0; j < 4; ++j)
        #pragma unroll
        for (int i = 0; i < 3; ++i) acc2[j][i] = 0.0f;

    #pragma unroll
    for (int c = 0; c < 8; ++c) {
        int k0  = (wv_ << 6) + (c << 3);
        int gk0 = k0 >> 2;
        float w2r[3][8], hr[4][8];
        #pragma unroll
        for (int i = 0; i < 3; ++i) {
            int p = 3 * pg + i, pk = p & 7;
            *reinterpret_cast<float4*>(&w2r[i][0]) =
                *reinterpret_cast<const float4*>(&w2t[p * 256 + (((gk0 + 0) ^ pk) << 2)]);
            *reinterpret_cast<float4*>(&w2r[i][4]) =
                *reinterpret_cast<const float4*>(&w2t[p * 256 + (((gk0 + 1) ^ pk) << 2)]);
        }
        #pragma unroll
        for (int j = 0; j < 4; ++j) {
            int bb = 4 * bq + j;
            *reinterpret_cast<float4*>(&hr[j][0]) =
                *reinterpret_cast<const float4*>(&h_s[bb * 256 + (((gk0 + 0) ^ bq) << 2)]);
            *reinterpret_cast<float4*>(&hr[j][4]) =
                *reinterpret_cast<const float4*>(&h_s[bb * 256 + (((gk0 + 1) ^ bq) << 2)]);
        }
        #pragma unroll
        for (int kk = 0; kk < 8; ++kk)
            #pragma unroll
            for (int j = 0; j < 4; ++j)
                #pragma unroll
                for (int i = 0; i < 3; ++i)
                    acc2[j][i] = fmaf(hr[j][kk], w2r[i][kk], acc2[j][i]);
    }
    __syncthreads();
    #pragma unroll
    for (int j = 0; j < 4; ++j)
        #pragma unroll
        for (int i = 0; i < 3; ++i)
            part[((wv_ << 5) + 4 * bq + j) * PK_TOT + 3 * pg + i] = acc2[j][i];
    __syncthreads();

    {
        const int eb = tid >> 3;
        const int ej = tid & 7;
        float rawa = b2[(size_t)r * PK_TOT + ej];
        float rawb = b2[(size_t)r * PK_TOT + 8 + ej];
        float rawr = b2[(size_t)r * PK_TOT + 16 + ej];
        #pragma unroll
        for (int w = 0; w < 4; ++w) {
            rawa += part[((w << 5) + eb) * PK_TOT + ej];
            rawb += part[((w << 5) + eb) * PK_TOT + 8 + ej];
            rawr += part[((w << 5) + eb) * PK_TOT + 16 + ej];
        }
        float zi = z_t[(r + 1) * 32 + eb];
        float t  = tanf((zi - PI_F) * 0.5f);
        float al = expf(rawa);
        float g  = fmaf(al, t, rawb);
        float X  = 2.0f * atanf(g) + PI_F;
        float dv = al * (1.0f + t * t) / (1.0f + g * g);
        float m = rawr;
        m = fmaxf(m, __shfl_xor(m, 1));
        m = fmaxf(m, __shfl_xor(m, 2));
        m = fmaxf(m, __shfl_xor(m, 4));
        float e  = expf(rawr - m);
        float se = e, sx = e * X, sd = e * dv;
        se += __shfl_xor(se, 1); se += __shfl_xor(se, 2); se += __shfl_xor(se, 4);
        sx += __shfl_xor(sx, 1); sx += __shfl_xor(sx, 2); sx += __shfl_xor(sx, 4);
        sd += __shfl_xor(sd, 1); sd += __shfl_xor(sd, 2); sd += __shfl_xor(sd, 4);
        if (ej == 0) {
            int gb = b0 + eb;
            out[(size_t)gb * D_TOT + (r + 1)] = sx / se;
            atomicAdd(&out[(size_t)B_TOT * D_TOT + gb], logf(sd / se));
        }
    }
}

extern "C" void kernel_launch(void* const* d_in, const int* in_sizes, int n_in,
                              void* d_out, int out_size, void* d_ws, size_t ws_size,
                              hipStream_t stream) {
    const float* z  = (const float*)d_in[0];
    const float* W1 = (const float*)d_in[1];
    const float* b1 = (const float*)d_in[2];
    const float* W2 = (const float*)d_in[3];
    const float* b2 = (const float*)d_in[4];
    float* out = (float*)d_out;

    init_out_kernel<<<dim3(B_TOT / 256), dim3(256), 0, stream>>>(out);
    if (ws_size >= (size_t)WS_NEED) {
        prep_weights<<<dim3(756), dim3(256), 0, stream>>>(W1, b1, W2, (unsigned int*)d_ws);
        flow_mfma<<<dim3(B_TOT / 64, R_TOT), dim3(256), 0, stream>>>(
            z, (const unsigned int*)d_ws, b2, out);
    } else {
        flow_fp32<<<dim3(B_TOT / 32, R_TOT), dim3(256), 0, stream>>>(z, W1, b1, W2, b2, out);
    }
}

// Round 10
// 103.499 us; speedup vs baseline: 4.8328x; 1.0724x over previous
//
#include <hip/hip_runtime.h>
#include <math.h>
#include <type_traits>

typedef __bf16 bf16x8 __attribute__((ext_vector_type(8)));
typedef float f32x4 __attribute__((ext_vector_type(4)));
typedef unsigned int u32x4 __attribute__((ext_vector_type(4)));

#define B_TOT 16384
#define D_TOT 64
#define R_TOT 63
#define H_TOT 256
#define PK_TOT 24
#define PI_F 3.14159265358979323846f

// ws layout (u32 units): W1F frags [((r*16+nt)*2+t)] then W2F frags [(r*2+nt2)*8+ks]
// all single-plane RTNE bf16.
#define W2F_BASE_U32 516096u
#define WS_NEED 3096576u

#define MFMA16(a, b, c) __builtin_amdgcn_mfma_f32_16x16x32_bf16((a), (b), (c), 0, 0, 0)

__device__ __forceinline__ unsigned short bf16_rtne(float f) {
    unsigned u = __float_as_uint(f);
    unsigned rr = u + 0x7FFFu + ((u >> 16) & 1u);
    return (unsigned short)(rr >> 16);
}

// one v_cvt_pk_bf16_f32: packs rtne(a) | rtne(b)<<16 (no builtin on gfx950)
__device__ __forceinline__ unsigned cvt_pk_bf16(float a, float b) {
    unsigned r;
    asm("v_cvt_pk_bf16_f32 %0, %1, %2" : "=v"(r) : "v"(a), "v"(b));
    return r;
}

__global__ void init_out_kernel(float* __restrict__ out) {
    int b = blockIdx.x * 256 + threadIdx.x;
    if (b < B_TOT) {
        out[(size_t)b * D_TOT] = 0.0f;            // x[:,0] = 0
        out[(size_t)B_TOT * D_TOT + b] = 0.0f;    // log_det = 0
    }
}

// ---------------- prep: weights -> single-plane RTNE bf16 MFMA fragments ----------------
// Bias trick: b1[r] in free padded K-row (d=31 for r<=30, d=63 for r>=31);
// main kernel forces staged z at that row to 1.0.
__global__ void prep_weights(const float* __restrict__ W1,
                             const float* __restrict__ b1,
                             const float* __restrict__ W2,
                             unsigned int* __restrict__ wsf)
{
    int gid = blockIdx.x * 256 + threadIdx.x;
    if (gid >= 193536) return;
    float v[8];
    unsigned int* dst;
    if (gid < 129024) {
        int lane = gid & 63;
        int q = gid >> 6;                  // frag idx 0..2015 = ((r*16+nt)*2+t)
        int t = q & 1; int qq = q >> 1;
        int nt = qq & 15; int r = qq >> 4;
        int n  = (nt << 4) + (lane & 15);
        int kb = (t << 5) + ((lane >> 4) << 3);
        int bias_d = (r <= 30) ? 31 : 63;
        #pragma unroll
        for (int j = 0; j < 8; ++j) {
            int d = kb + j;
            v[j] = (d <= r) ? W1[(size_t)(r * 64 + d) * 256 + n]
                 : (d == bias_d ? b1[(size_t)r * 256 + n] : 0.0f);
        }
        dst = wsf + (size_t)q * 256 + ((unsigned)lane << 2);
    } else {
        int g2 = gid - 129024;
        int lane = g2 & 63;
        int q = g2 >> 6;                   // frag idx 0..1007 = (r*2+nt)*8+ks
        int ks = q & 7; int qq = q >> 3;
        int nt = qq & 1; int r = qq >> 1;
        int n  = (nt << 4) + (lane & 15);
        int kb = (ks << 5) + ((lane >> 4) << 3);
        #pragma unroll
        for (int j = 0; j < 8; ++j) {
            int k = kb + j;
            v[j] = (n < PK_TOT) ? W2[(size_t)(r * 256 + k) * PK_TOT + n] : 0.0f;
        }
        dst = wsf + W2F_BASE_U32 + (size_t)q * 256 + ((unsigned)lane << 2);
    }
    unsigned hw[4];
    #pragma unroll
    for (int i = 0; i < 4; ++i)
        hw[i] = (unsigned)bf16_rtne(v[2 * i]) | ((unsigned)bf16_rtne(v[2 * i + 1]) << 16);
    *reinterpret_cast<u32x4*>(dst) = u32x4{hw[0], hw[1], hw[2], hw[3]};
}

// ---------------- main MFMA kernel: block = 64 batches x TWO r-values, 4 waves ----------------
// r-pairing within one bias class (z tile identical): y<15 -> (2y,2y+1); y==15 -> (30);
// y>=16 -> (2y-1,2y). Stage z + t-caches once, run per-r pipeline twice; log_det
// accumulated in registers across both r (one atomicAdd per batch per block).
// LDS: z [0,8K), h/partials [8K,24K), t-cache [24K, 24K+512B).
__global__ __launch_bounds__(256, 4) void flow_mfma(
    const float* __restrict__ z, const unsigned int* __restrict__ wsf,
    const float* __restrict__ b2, float* __restrict__ out)
{
    const int y   = blockIdx.y;
    int r0, r1;
    if (y < 15)       { r0 = 2 * y;     r1 = 2 * y + 1; }
    else if (y == 15) { r0 = 30;        r1 = -1;        }
    else              { r0 = 2 * y - 1; r1 = 2 * y;     }
    const int bias_d = (y <= 15) ? 31 : 63;

    const int b0  = blockIdx.x << 6;
    const int tid = threadIdx.x;
    const int w   = tid >> 6;
    const int l   = tid & 63;
    const int l15 = l & 15, l4 = l >> 4, key = l & 7;

    __shared__ __align__(16) unsigned char sm[25088];
    float* tls = reinterpret_cast<float*>(sm + 24576);   // t per (r-slot, batch): [2][64]

    // ---- stage z as single-plane RTNE bf16 (shared by r0,r1); t computed once/batch/r ----
    {
        const int m  = tid >> 2;
        const int dq = (tid & 3) << 4;
        const float* zp = z + (size_t)(b0 + m) * 64 + dq;
        const int mkey = m & 7;
        const int rel  = bias_d - dq;           // in [0,16) only for the owning thread
        const int tel0 = (r0 + 1) - dq;
        const int tel1 = (r1 + 1) - dq;         // r1=-1 -> only dq==0 matches; writes unread slot
        #pragma unroll
        for (int qq = 0; qq < 4; ++qq) {
            float4 val = *reinterpret_cast<const float4*>(zp + (qq << 2));
            int d0 = dq + (qq << 2);
            float vv[4] = {val.x, val.y, val.z, val.w};
            // t = tan((zi-pi)/2) = -cos(zi/2)/sin(zi/2) from pre-rounding f32;
            // MUST precede the bias overwrite (r+1 can equal bias_d).
            if ((tel0 >> 2) == qq) {
                float zi = vv[tel0 & 3];
                float s, c;
                __sincosf(zi * 0.5f, &s, &c);
                float t = -c * __builtin_amdgcn_rcpf(s);
                tls[m] = fminf(fmaxf(t, -1e8f), 1e8f);
            }
            if ((tel1 >> 2) == qq) {
                float zi = vv[tel1 & 3];
                float s, c;
                __sincosf(zi * 0.5f, &s, &c);
                float t = -c * __builtin_amdgcn_rcpf(s);
                tls[64 + m] = fminf(fmaxf(t, -1e8f), 1e8f);
            }
            if ((rel >> 2) == qq) vv[rel & 3] = 1.0f;   // bias row (exact in bf16)
            uint2 hv;
            hv.x = cvt_pk_bf16(vv[0], vv[1]);
            hv.y = cvt_pk_bf16(vv[2], vv[3]);
            int off = (m << 7) + ((((d0 >> 3)) ^ mkey) << 4) + (((d0 >> 2) & 1) << 3);
            *reinterpret_cast<uint2*>(sm + off) = hv;
        }
    }
    __syncthreads();

    const int ej = tid & 7;
    float ld0 = 0.0f, ld1 = 0.0f;   // log_det accum for batch (tid>>3) and (tid>>3)+32

    #pragma unroll 1
    for (int ri = 0; ri < 2; ++ri) {
        const int r = ri ? r1 : r0;
        if (r < 0) break;           // y==15: single r

        const unsigned int* w1b = wsf + (size_t)((r * 16 + (w << 2)) * 2) * 256 + (l << 2);
        const unsigned int* w2b = wsf + W2F_BASE_U32 + (size_t)(r * 16) * 256 + (l << 2);
        const float b2a = b2[(size_t)r * 24 + ej];
        const float b2b = b2[(size_t)r * 24 + 8 + ej];
        const float b2r = b2[(size_t)r * 24 + 16 + ej];

        #pragma unroll 1
        for (int mh = 0; mh < 2; ++mh) {
            // ---- GEMM1 for batches mh*32..+32: D1[n][m] = sum_d W1m[d][n]*z[m][d] ----
            f32x4 acc1[4][2];
            #pragma unroll
            for (int a = 0; a < 4; ++a)
                #pragma unroll
                for (int b = 0; b < 2; ++b) acc1[a][b] = f32x4{0.f, 0.f, 0.f, 0.f};

            auto run_gemm1 = [&](auto FULLC) {
                constexpr int NT = decltype(FULLC)::value ? 2 : 1;
                #pragma unroll
                for (int t = 0; t < NT; ++t) {
                    bf16x8 zf[2];   // [mt] single plane
                    #pragma unroll
                    for (int mt = 0; mt < 2; ++mt) {
                        int m = (mh << 5) + (mt << 4) + l15;
                        int off = (m << 7) + ((((t << 2) + l4) ^ key) << 4);
                        zf[mt] = __builtin_bit_cast(bf16x8, *reinterpret_cast<u32x4*>(sm + off));
                    }
                    #pragma unroll
                    for (int ntl = 0; ntl < 4; ++ntl) {
                        bf16x8 af = __builtin_bit_cast(bf16x8,
                            *reinterpret_cast<const u32x4*>(w1b + (((ntl << 1) + t) << 8)));
                        #pragma unroll
                        for (int mt = 0; mt < 2; ++mt)
                            acc1[ntl][mt] = MFMA16(af, zf[mt], acc1[ntl][mt]);
                    }
                }
            };
            if (r >= 31) run_gemm1(std::true_type{});
            else         run_gemm1(std::false_type{});

            // ---- relu + RTNE bf16, write h tile [32][256]bf16 at 8192 (row 512B) ----
            #pragma unroll
            for (int ntl = 0; ntl < 4; ++ntl) {
                #pragma unroll
                for (int mt = 0; mt < 2; ++mt) {
                    float v0 = fmaxf(acc1[ntl][mt][0], 0.0f);
                    float v1 = fmaxf(acc1[ntl][mt][1], 0.0f);
                    float v2 = fmaxf(acc1[ntl][mt][2], 0.0f);
                    float v3 = fmaxf(acc1[ntl][mt][3], 0.0f);
                    uint2 hv;
                    hv.x = cvt_pk_bf16(v0, v1);
                    hv.y = cvt_pk_bf16(v2, v3);
                    int mloc = (mt << 4) + l15;
                    int g    = (w << 3) + (ntl << 1) + (l4 >> 1);           // granule 0..31
                    int off  = 8192 + (mloc << 9)
                             + (((g & 24) | ((g ^ key) & 7)) << 4) + ((l4 & 1) << 3);
                    *reinterpret_cast<uint2*>(sm + off) = hv;
                }
            }
            __syncthreads();

            // ---- gemm2 full-K, k-split: wave w covers k = w*64..w*64+63 ----
            f32x4 acc2[2][2];
            #pragma unroll
            for (int a = 0; a < 2; ++a)
                #pragma unroll
                for (int b = 0; b < 2; ++b) acc2[a][b] = f32x4{0.f, 0.f, 0.f, 0.f};

            #pragma unroll
            for (int kk = 0; kk < 2; ++kk) {
                const int ks = (w << 1) + kk;
                bf16x8 wf[2];
                #pragma unroll
                for (int nt2 = 0; nt2 < 2; ++nt2)
                    wf[nt2] = __builtin_bit_cast(bf16x8,
                        *reinterpret_cast<const u32x4*>(w2b + (((nt2 << 3) + ks) << 8)));
                bf16x8 hfr[2];
                #pragma unroll
                for (int mt = 0; mt < 2; ++mt) {
                    int mloc = (mt << 4) + l15;
                    int g    = (ks << 2) + l4;
                    int off  = 8192 + (mloc << 9)
                             + (((g & 24) | ((g ^ key) & 7)) << 4);
                    hfr[mt] = __builtin_bit_cast(bf16x8, *reinterpret_cast<u32x4*>(sm + off));
                }
                #pragma unroll
                for (int nt2 = 0; nt2 < 2; ++nt2)
                    #pragma unroll
                    for (int mt = 0; mt < 2; ++mt)
                        acc2[nt2][mt] = MFMA16(wf[nt2], hfr[mt], acc2[nt2][mt]);
            }
            __syncthreads();   // h reads done; alias region as partials

            // ---- partials [4 waves][32 m][32 p-pad] f32 = 16KB over h region ----
            #pragma unroll
            for (int nt2 = 0; nt2 < 2; ++nt2)
                #pragma unroll
                for (int mt = 0; mt < 2; ++mt) {
                    int row = (w << 5) + (mt << 4) + l15;
                    int off = 8192 + (row << 7) + ((((nt2 << 2) + l4) ^ key) << 4);
                    *reinterpret_cast<f32x4*>(sm + off) = acc2[nt2][mt];
                }
            __syncthreads();

            // ---- flow epilogue: thread = (mloc = tid>>3, j = tid&7) ----
            {
                const int mloc = tid >> 3;
                const int j    = ej;
                const int mk   = mloc & 7;
                float ra = b2a, rb = b2b, rr = b2r;
                #pragma unroll
                for (int w4 = 0; w4 < 4; ++w4) {
                    const int base = 8192 + (((w4 << 5) + mloc) << 7);
                    const int sub  = (j & 3) << 2;
                    ra += *reinterpret_cast<float*>(sm + base + ((((j) >> 2) ^ mk) << 4) + sub);
                    rb += *reinterpret_cast<float*>(sm + base + (((2 + (j >> 2)) ^ mk) << 4) + sub);
                    rr += *reinterpret_cast<float*>(sm + base + (((4 + (j >> 2)) ^ mk) << 4) + sub);
                }
                int gb = b0 + (mh << 5) + mloc;
                float t  = tls[(ri << 6) + (mh << 5) + mloc];
                float al = __expf(ra);
                float g  = fmaf(al, t, rb);
                float X  = 2.0f * atanf(g) + PI_F;
                float dv = al * fmaf(t, t, 1.0f) * __builtin_amdgcn_rcpf(fmaf(g, g, 1.0f));
                float mx = rr;
                mx = fmaxf(mx, __shfl_xor(mx, 1));
                mx = fmaxf(mx, __shfl_xor(mx, 2));
                mx = fmaxf(mx, __shfl_xor(mx, 4));
                float e = __expf(rr - mx);
                float se = e, sx = e * X, sd = e * dv;
                se += __shfl_xor(se, 1); se += __shfl_xor(se, 2); se += __shfl_xor(se, 4);
                sx += __shfl_xor(sx, 1); sx += __shfl_xor(sx, 2); sx += __shfl_xor(sx, 4);
                sd += __shfl_xor(sd, 1); sd += __shfl_xor(sd, 2); sd += __shfl_xor(sd, 4);
                if (j == 0) {
                    float rse = __builtin_amdgcn_rcpf(se);
                    out[(size_t)gb * D_TOT + r + 1] = sx * rse;
                    float ldv = __logf(sd * rse);
                    if (mh == 0) ld0 += ldv; else ld1 += ldv;
                }
            }
            __syncthreads();   // partial region reused as h tile next mh/r
        }
    }

    // ---- one atomicAdd per batch per block (both r contributions summed) ----
    if (ej == 0) {
        const int mloc = tid >> 3;
        atomicAdd(&out[(size_t)B_TOT * D_TOT + b0 + mloc], ld0);
        atomicAdd(&out[(size_t)B_TOT * D_TOT + b0 + 32 + mloc], ld1);
    }
}

// ---------------- fp32 fallback (round-1 kernel, known-correct) ----------------
__global__ __launch_bounds__(256, 2) void flow_fp32(
    const float* __restrict__ z,  const float* __restrict__ W1,
    const float* __restrict__ b1, const float* __restrict__ W2,
    const float* __restrict__ b2, float* __restrict__ out)
{
    const int r   = blockIdx.y;
    const int b0  = blockIdx.x * 32;
    const int tid = threadIdx.x;

    __shared__ float smem[16384];
    float* z_t  = smem;
    float* h_s  = smem + 2048;
    float* w2t  = smem + 2048 + 8192;
    float* part = w2t;

    #pragma unroll
    for (int it = 0; it < 2; ++it) {
        int idx4 = it * 256 + tid;
        int brow = idx4 >> 4;
        int dq   = (idx4 & 15) << 2;
        float4 v = *reinterpret_cast<const float4*>(&z[(size_t)(b0 + brow) * D_TOT + dq]);
        z_t[(dq + 0) * 32 + brow] = v.x;
        z_t[(dq + 1) * 32 + brow] = v.y;
        z_t[(dq + 2) * 32 + brow] = v.z;
        z_t[(dq + 3) * 32 + brow] = v.w;
    }
    #pragma unroll
    for (int it = 0; it < 6; ++it) {
        int idx4 = it * 256 + tid;
        int k  = idx4 / 6;
        int pq = (idx4 - k * 6) << 2;
        float4 v = *reinterpret_cast<const float4*>(&W2[(size_t)(r * H_TOT + k) * PK_TOT + pq]);
        int gk = k >> 2, kq = k & 3;
        w2t[(pq + 0) * 256 + (((gk) ^ ((pq + 0) & 7)) << 2) + kq] = v.x;
        w2t[(pq + 1) * 256 + (((gk) ^ ((pq + 1) & 7)) << 2) + kq] = v.y;
        w2t[(pq + 2) * 256 + (((gk) ^ ((pq + 2) & 7)) << 2) + kq] = v.z;
        w2t[(pq + 3) * 256 + (((gk) ^ ((pq + 3) & 7)) << 2) + kq] = v.w;
    }
    __syncthreads();

    const int rg = tid & 15;
    const int cg = tid >> 4;
    float acc[2][16];
    #pragma unroll
    for (int j = 0; j < 2; ++j)
        #pragma unroll
        for (int i = 0; i < 16; ++i) acc[j][i] = 0.0f;

    const float* w1p = W1 + (size_t)(r * D_TOT) * H_TOT + (cg << 4);
    #pragma unroll 4
    for (int d = 0; d <= r; ++d) {
        float2 zv = *reinterpret_cast<const float2*>(&z_t[d * 32 + (rg << 1)]);
        const float* wrow = w1p + (size_t)d * H_TOT;
        float wv[16];
        *reinterpret_cast<float4*>(&wv[0])  = *reinterpret_cast<const float4*>(wrow + 0);
        *reinterpret_cast<float4*>(&wv[4])  = *reinterpret_cast<const float4*>(wrow + 4);
        *reinterpret_cast<float4*>(&wv[8])  = *reinterpret_cast<const float4*>(wrow + 8);
        *reinterpret_cast<float4*>(&wv[12]) = *reinterpret_cast<const float4*>(wrow + 12);
        #pragma unroll
        for (int i = 0; i < 16; ++i) {
            acc[0][i] = fmaf(zv.x, wv[i], acc[0][i]);
            acc[1][i] = fmaf(zv.y, wv[i], acc[1][i]);
        }
    }
    {
        const int key = (rg >> 1) & 7;
        #pragma unroll
        for (int gi = 0; gi < 4; ++gi) {
            float4 bv = *reinterpret_cast<const float4*>(&b1[(size_t)r * H_TOT + (cg << 4) + (gi << 2)]);
            #pragma unroll
            for (int j = 0; j < 2; ++j) {
                float4 v;
                v.x = fmaxf(acc[j][4 * gi + 0] + bv.x, 0.0f);
                v.y = fmaxf(acc[j][4 * gi + 1] + bv.y, 0.0f);
                v.z = fmaxf(acc[j][4 * gi + 2] + bv.z, 0.0f);
                v.w = fmaxf(acc[j][4 * gi + 3] + bv.w, 0.0f);
                int bb = (rg << 1) + j;
                int g  = ((cg << 2) + gi) ^ key;
                *reinterpret_cast<float4*>(&h_s[bb * 256 + (g << 2)]) = v;
            }
        }
    }
    __syncthreads();

    const int wv_ = tid >> 6;
    const int ln  = tid & 63;
    const int bq  = ln & 7;
    const int pg  = ln >> 3;
    float acc2[4][3];
    #pragma unroll
    for (int j = 0; j < 4; ++j)
        #pragma unroll
        for (int i = 0; i < 3; ++i) acc2[j][i] = 0.0f;

    #pragma unroll
    for (int c = 0; c < 8; ++c) {
        int k0  = (wv_ << 6) + (c << 3);
        int gk0 = k0 >> 2;
        float w2r[3][8], hr[4][8];
        #pragma unroll
        for (int i = 0; i < 3; ++i) {
            int p = 3 * pg + i, pk = p & 7;
            *reinterpret_cast<float4*>(&w2r[i][0]) =
                *reinterpret_cast<const float4*>(&w2t[p * 256 + (((gk0 + 0) ^ pk) << 2)]);
            *reinterpret_cast<float4*>(&w2r[i][4]) =
                *reinterpret_cast<const float4*>(&w2t[p * 256 + (((gk0 + 1) ^ pk) << 2)]);
        }
        #pragma unroll
        for (int j = 0; j < 4; ++j) {
            int bb = 4 * bq + j;
            *reinterpret_cast<float4*>(&hr[j][0]) =
                *reinterpret_cast<const float4*>(&h_s[bb * 256 + (((gk0 + 0) ^ bq) << 2)]);
            *reinterpret_cast<float4*>(&hr[j][4]) =
                *reinterpret_cast<const float4*>(&h_s[bb * 256 + (((gk0 + 1) ^ bq) << 2)]);
        }
        #pragma unroll
        for (int kk = 0; kk < 8; ++kk)
            #pragma unroll
            for (int j = 0; j < 4; ++j)
                #pragma unroll
                for (int i = 0; i < 3; ++i)
                    acc2[j][i] = fmaf(hr[j][kk], w2r[i][kk], acc2[j][i]);
    }
    __syncthreads();
    #pragma unroll
    for (int j = 0; j < 4; ++j)
        #pragma unroll
        for (int i = 0; i < 3; ++i)
            part[((wv_ << 5) + 4 * bq + j) * PK_TOT + 3 * pg + i] = acc2[j][i];
    __syncthreads();

    {
        const int eb = tid >> 3;
        const int ej = tid & 7;
        float rawa = b2[(size_t)r * PK_TOT + ej];
        float rawb = b2[(size_t)r * PK_TOT + 8 + ej];
        float rawr = b2[(size_t)r * PK_TOT + 16 + ej];
        #pragma unroll
        for (int w = 0; w < 4; ++w) {
            rawa += part[((w << 5) + eb) * PK_TOT + ej];
            rawb += part[((w << 5) + eb) * PK_TOT + 8 + ej];
            rawr += part[((w << 5) + eb) * PK_TOT + 16 + ej];
        }
        float zi = z_t[(r + 1) * 32 + eb];
        float t  = tanf((zi - PI_F) * 0.5f);
        float al = expf(rawa);
        float g  = fmaf(al, t, rawb);
        float X  = 2.0f * atanf(g) + PI_F;
        float dv = al * (1.0f + t * t) / (1.0f + g * g);
        float m = rawr;
        m = fmaxf(m, __shfl_xor(m, 1));
        m = fmaxf(m, __shfl_xor(m, 2));
        m = fmaxf(m, __shfl_xor(m, 4));
        float e  = expf(rawr - m);
        float se = e, sx = e * X, sd = e * dv;
        se += __shfl_xor(se, 1); se += __shfl_xor(se, 2); se += __shfl_xor(se, 4);
        sx += __shfl_xor(sx, 1); sx += __shfl_xor(sx, 2); sx += __shfl_xor(sx, 4);
        sd += __shfl_xor(sd, 1); sd += __shfl_xor(sd, 2); sd += __shfl_xor(sd, 4);
        if (ej == 0) {
            int gb = b0 + eb;
            out[(size_t)gb * D_TOT + (r + 1)] = sx / se;
            atomicAdd(&out[(size_t)B_TOT * D_TOT + gb], logf(sd / se));
        }
    }
}

extern "C" void kernel_launch(void* const* d_in, const int* in_sizes, int n_in,
                              void* d_out, int out_size, void* d_ws, size_t ws_size,
                              hipStream_t stream) {
    const float* z  = (const float*)d_in[0];
    const float* W1 = (const float*)d_in[1];
    const float* b1 = (const float*)d_in[2];
    const float* W2 = (const float*)d_in[3];
    const float* b2 = (const float*)d_in[4];
    float* out = (float*)d_out;

    init_out_kernel<<<dim3(B_TOT / 256), dim3(256), 0, stream>>>(out);
    if (ws_size >= (size_t)WS_NEED) {
        prep_weights<<<dim3(756), dim3(256), 0, stream>>>(W1, b1, W2, (unsigned int*)d_ws);
        flow_mfma<<<dim3(B_TOT / 64, 32), dim3(256), 0, stream>>>(
            z, (const unsigned int*)d_ws, b2, out);
    } else {
        flow_fp32<<<dim3(B_TOT / 32, R_TOT), dim3(256), 0, stream>>>(z, W1, b1, W2, b2, out);
    }
}